// Round 11
// baseline (800.392 us; speedup 1.0000x reference)
//
#include <hip/hip_runtime.h>

using u16 = unsigned short;

constexpr int CIN = 16, COUT = 32, COFF = 16;
constexpr int D = 32, H = 128, W = 160;
constexpr int HW = H * W;         // 20480
constexpr int DHW = D * HW;       // 655360
constexpr int NOUT = COUT * DHW;  // 20971520
constexpr float EPS = 1e-5f;

// ---- workspace layout (byte offsets) ----
constexpr size_t WF_OFF = 16384;
constexpr size_t DFRAG_OFF = 243712;       // packed deform A-frags, 10240 B (< A1CH_OFF)
constexpr size_t A1CH_OFF = 262144;        // a1ch [pix][32ch] bf16: 41,943,040
constexpr size_t XCH16_OFF = 42205184;     // xch16 [pix][16ch] bf16: 20,971,520
constexpr size_t FRAG2P_W2 = 84148224;     // frag slots, two-pass path
constexpr size_t FRAG2P_WD = 84203520;
constexpr size_t NEED_2PASS = 84258816;
constexpr size_t STA_OFF = 63176704;       // fp32 A
constexpr size_t STB_OFF = 147062784;      // fp32 B
constexpr size_t FRAGS_W2 = 230948864;     // frag slots, store path (after B)
constexpr size_t FRAGS_WD = 231004160;
constexpr size_t NEED_STORE = 231059456;
// WF float-offsets
constexpr int WOFF_O = 0, WREG_O = 2592, W2_O = 7200, WD_O = 34848;
constexpr int G1_O = 48672, B1_O = 48704, G2_O = 48736, B2_O = 48768, GD_O = 48800, BD_O = 48832;
constexpr int WOFFT_O = 49152;             // transposed offset weights
constexpr int FLAG_SLOT = 3000;

typedef short bf16x8 __attribute__((ext_vector_type(8)));
typedef float f32x4 __attribute__((ext_vector_type(4)));
typedef u16 u16x8 __attribute__((ext_vector_type(8)));

static __device__ __forceinline__ float bf2f(u16 h) {
  unsigned u = ((unsigned)h) << 16;
  float f;
  __builtin_memcpy(&f, &u, 4);
  return f;
}
static __device__ __forceinline__ u16 f2bf(float f) {
  unsigned u;
  __builtin_memcpy(&u, &f, 4);
  u += 0x7fffu + ((u >> 16) & 1u);
  return (u16)(u >> 16);
}
static __device__ __forceinline__ float ldin(const void* p, int i, int bf) {
  float r;
  if (bf) r = bf2f(((const u16*)p)[i]);
  else r = ((const float*)p)[i];
  return r;
}

__global__ __launch_bounds__(256) void zero_kernel(float* __restrict__ S) {
  S[blockIdx.x * 256 + threadIdx.x] = 0.f;
}

__global__ __launch_bounds__(256) void sniff_kernel(const u16* __restrict__ x,
                                                    int* __restrict__ flag) {
  __shared__ int sh[256];
  int cnt = 0;
  for (int i = threadIdx.x; i < 4096; i += 256) {
    int e = (x[i] >> 7) & 0xff;
    cnt += (e >= 96 && e <= 144) ? 1 : 0;
  }
  sh[threadIdx.x] = cnt;
  __syncthreads();
  for (int s = 128; s > 0; s >>= 1) {
    if (threadIdx.x < (unsigned)s) sh[threadIdx.x] += sh[threadIdx.x + s];
    __syncthreads();
  }
  if (threadIdx.x == 0) flag[0] = (sh[0] > 3072) ? 1 : 0;
}

// all 10 input conversions in one launch
__global__ __launch_bounds__(256) void cvt_all_kernel(
    const void* s0, const void* s1, const void* s2, const void* s3, const void* s4,
    const void* s5, const void* s6, const void* s7, const void* s8, const void* s9,
    float* __restrict__ WF, const int* __restrict__ flagp) {
  const int bf = flagp[0];
  int i = blockIdx.x * 256 + threadIdx.x;
  if (i < 2592) { WF[WOFF_O + i] = ldin(s0, i, bf); return; }
  i -= 2592;
  if (i < 4608) { WF[WREG_O + i] = ldin(s1, i, bf); return; }
  i -= 4608;
  if (i < 27648) { WF[W2_O + i] = ldin(s2, i, bf); return; }
  i -= 27648;
  if (i < 13824) { WF[WD_O + i] = ldin(s3, i, bf); return; }
  i -= 13824;
  if (i < 32) { WF[G1_O + i] = ldin(s4, i, bf); return; }
  i -= 32;
  if (i < 32) { WF[B1_O + i] = ldin(s5, i, bf); return; }
  i -= 32;
  if (i < 32) { WF[G2_O + i] = ldin(s6, i, bf); return; }
  i -= 32;
  if (i < 32) { WF[B2_O + i] = ldin(s7, i, bf); return; }
  i -= 32;
  if (i < 32) { WF[GD_O + i] = ldin(s8, i, bf); return; }
  i -= 32;
  if (i < 32) { WF[BD_O + i] = ldin(s9, i, bf); }
}

// all weight reshapes/packs in one launch (depends on cvt_all output)
__global__ __launch_bounds__(256) void prep_kernel(const float* __restrict__ WF,
                                                   float* __restrict__ wofft,
                                                   u16* __restrict__ w2frag,
                                                   u16* __restrict__ wdfrag,
                                                   u16* __restrict__ dfrag) {
  int i = blockIdx.x * 256 + threadIdx.x;
  if (i < 2592) {  // w_off [18][144] -> [144][18]
    int ch = i / 144, widx = i % 144;
    wofft[widx * 18 + ch] = WF[WOFF_O + i];
    return;
  }
  i -= 2592;
  if (i < 27648) {  // pack w2 frags (nci=32)
    int j = i & 7, l = (i >> 3) & 63, cotile = (i >> 9) & 1, tap = i >> 10;
    int co = cotile * 16 + (l & 15);
    int k = (l >> 4) * 8 + j;
    w2frag[i] = f2bf(WF[W2_O + (co * 32 + k) * 27 + tap]);
    return;
  }
  i -= 27648;
  if (i < 27648) {  // pack wd frags (nci=16, zero-pad k>=16)
    int j = i & 7, l = (i >> 3) & 63, cotile = (i >> 9) & 1, tap = i >> 10;
    int co = cotile * 16 + (l & 15);
    int k = (l >> 4) * 8 + j;
    float v = (k < 16) ? WF[WD_O + (co * 16 + k) * 27 + tap] : 0.f;
    wdfrag[i] = f2bf(v);
    return;
  }
  i -= 27648;
  if (i < 5120) {  // pack deform A-frags: k' = tap*16+ci, K padded 144->160
    int j = i & 7, l = (i >> 3) & 63, ct = (i >> 9) & 1, c = i >> 10;
    int k = c * 32 + (l >> 4) * 8 + j;
    int co = ct * 16 + (l & 15);
    float v = (k < 144) ? WF[WREG_O + co * 144 + (k & 15) * 9 + (k >> 4)] : 0.f;
    dfrag[i] = f2bf(v);
  }
}

// transpose 16-channel channel-major input -> [pix][16ch] bf16 (32 B/pixel)
__global__ __launch_bounds__(256) void chpose_kernel(const void* __restrict__ src,
                                                     u16* __restrict__ dst,
                                                     const int* __restrict__ flagp) {
  const int bf = flagp[0];
  __shared__ u16 lt[16][258];
  const int base = blockIdx.x * 256;
  const int t = threadIdx.x;
#pragma unroll
  for (int ci = 0; ci < 16; ci++) lt[ci][t] = f2bf(ldin(src, ci * DHW + base + t, bf));
  __syncthreads();
  const size_t pb = (size_t)(base + t) * 16;
  uint4 u0, u1;
  u0.x = (unsigned)lt[0][t] | ((unsigned)lt[1][t] << 16);
  u0.y = (unsigned)lt[2][t] | ((unsigned)lt[3][t] << 16);
  u0.z = (unsigned)lt[4][t] | ((unsigned)lt[5][t] << 16);
  u0.w = (unsigned)lt[6][t] | ((unsigned)lt[7][t] << 16);
  u1.x = (unsigned)lt[8][t] | ((unsigned)lt[9][t] << 16);
  u1.y = (unsigned)lt[10][t] | ((unsigned)lt[11][t] << 16);
  u1.z = (unsigned)lt[12][t] | ((unsigned)lt[13][t] << 16);
  u1.w = (unsigned)lt[14][t] | ((unsigned)lt[15][t] << 16);
  *(uint4*)(dst + pb) = u0;
  *(uint4*)(dst + pb + 8) = u1;
}

// Deformable conv v3: offset-conv + bilinear sampling on VALU (channel-major
// coalesced loads, proven), but the 32-co accumulate moved to MFMA:
// A1[co][pix] = W(32x144) x S(144xpix), K padded to 160, 5 chunks of 32.
// Per chunk each thread samples 2 taps x 16 ci for ITS pixel into LDS
// [pixel][k] bf16 (stride 40 u16); waves own disjoint LDS rows -> no barriers.
__global__ __launch_bounds__(256) void deform_mfma_kernel(const void* __restrict__ x,
                                                          const void* __restrict__ f,
                                                          const float* __restrict__ w_off_t,
                                                          const u16* __restrict__ dfrag,
                                                          u16* __restrict__ a1ch,
                                                          const int* __restrict__ flagp,
                                                          float* __restrict__ S) {
  __shared__ u16 slds[256 * 40];  // 20480 B
  __shared__ float ls[128], lq[128];
  const int bf = flagp[0];
  const int hw = blockIdx.x;                 // grid = 2560, %8 == 0
  const int bid = (hw & 7) * 320 + (hw >> 3);
  const int d = bid / 80;
  const int p = (bid % 80) * 256 + threadIdx.x;
  const int y = p / W;
  const int xx = p % W;
  const int dbase = d * HW;

  // ---- offset conv (VALU, unchanged) ----
  float doff[18];
#pragma unroll
  for (int t = 0; t < 18; t++) doff[t] = 0.f;
  for (int ci = 0; ci < COFF; ci++) {
    const int fbase = ci * DHW + dbase;
#pragma unroll
    for (int ki = 0; ki < 3; ki++) {
      int yy = y - 1 + ki;
      bool yok = (unsigned)yy < (unsigned)H;
#pragma unroll
      for (int kj = 0; kj < 3; kj++) {
        int xj = xx - 1 + kj;
        float v = (yok && (unsigned)xj < (unsigned)W) ? ldin(f, fbase + yy * W + xj, bf) : 0.f;
        int widx = ci * 9 + ki * 3 + kj;
#pragma unroll
        for (int t = 0; t < 18; t++) doff[t] += v * w_off_t[widx * 18 + t];
      }
    }
  }

  const int l = threadIdx.x & 63;
  const int wv = threadIdx.x >> 6;
  const int n = l & 15, q = l >> 4;
  const bf16x8* dfv = (const bf16x8*)dfrag;

  f32x4 acc[4][2];
#pragma unroll
  for (int g = 0; g < 4; g++) {
    acc[g][0] = (f32x4){0.f, 0.f, 0.f, 0.f};
    acc[g][1] = (f32x4){0.f, 0.f, 0.f, 0.f};
  }

#pragma unroll
  for (int c = 0; c < 5; c++) {
    // sample taps 2c, 2c+1 for this thread's pixel -> LDS
#pragma unroll
    for (int hf = 0; hf < 2; hf++) {
      const int t = 2 * c + hf;
      uint4 w0, w1;
      if (t < 9) {
        float dy = fminf(fmaxf(doff[2 * t], -1.f), 1.f);
        float dx = fminf(fmaxf(doff[2 * t + 1], -1.f), 1.f);
        float py = (float)(y - 1 + t / 3) + dy;
        float px = (float)(xx - 1 + t % 3) + dx;
        float y0f = floorf(py), x0f = floorf(px);
        float wy1 = py - y0f, wx1 = px - x0f;
        int y0 = (int)y0f, x0i = (int)x0f;
        int y1 = y0 + 1, x1 = x0i + 1;
        bool y0v = (unsigned)y0 < (unsigned)H, y1v = (unsigned)y1 < (unsigned)H;
        bool x0v = (unsigned)x0i < (unsigned)W, x1v = (unsigned)x1 < (unsigned)W;
        float c00 = (y0v && x0v) ? (1.f - wy1) * (1.f - wx1) : 0.f;
        float c01 = (y0v && x1v) ? (1.f - wy1) * wx1 : 0.f;
        float c10 = (y1v && x0v) ? wy1 * (1.f - wx1) : 0.f;
        float c11 = (y1v && x1v) ? wy1 * wx1 : 0.f;
        int y0c = min(max(y0, 0), H - 1) * W, y1c = min(max(y1, 0), H - 1) * W;
        int x0c = min(max(x0i, 0), W - 1), x1c = min(max(x1, 0), W - 1);

        u16 sv[16];
#pragma unroll
        for (int ci = 0; ci < CIN; ci++) {
          const int xbase = ci * DHW + dbase;
          float s = c00 * ldin(x, xbase + y0c + x0c, bf) + c01 * ldin(x, xbase + y0c + x1c, bf) +
                    c10 * ldin(x, xbase + y1c + x0c, bf) + c11 * ldin(x, xbase + y1c + x1c, bf);
          sv[ci] = f2bf(s);
        }
        w0.x = (unsigned)sv[0] | ((unsigned)sv[1] << 16);
        w0.y = (unsigned)sv[2] | ((unsigned)sv[3] << 16);
        w0.z = (unsigned)sv[4] | ((unsigned)sv[5] << 16);
        w0.w = (unsigned)sv[6] | ((unsigned)sv[7] << 16);
        w1.x = (unsigned)sv[8] | ((unsigned)sv[9] << 16);
        w1.y = (unsigned)sv[10] | ((unsigned)sv[11] << 16);
        w1.z = (unsigned)sv[12] | ((unsigned)sv[13] << 16);
        w1.w = (unsigned)sv[14] | ((unsigned)sv[15] << 16);
      } else {
        w0.x = w0.y = w0.z = w0.w = 0u;
        w1 = w0;
      }
      char* wp = (char*)slds + threadIdx.x * 80 + hf * 32;
      *(uint4*)wp = w0;
      *(uint4*)(wp + 16) = w1;
    }
    // MFMA over this wave's 64 pixels (4 groups x 2 co-tiles); wave-local LDS,
    // compiler inserts lgkmcnt, no block barrier needed.
    bf16x8 a0 = dfv[(c * 2 + 0) * 64 + l];
    bf16x8 a1f = dfv[(c * 2 + 1) * 64 + l];
#pragma unroll
    for (int g = 0; g < 4; g++) {
      const bf16x8 b = *(const bf16x8*)((const char*)slds + (wv * 64 + g * 16 + n) * 80 + q * 16);
      acc[g][0] = __builtin_amdgcn_mfma_f32_16x16x32_bf16(a0, b, acc[g][0], 0, 0, 0);
      acc[g][1] = __builtin_amdgcn_mfma_f32_16x16x32_bf16(a1f, b, acc[g][1], 0, 0, 0);
    }
  }

  // store channels-last bf16 + BN1 stats (on bf16-rounded values)
  u16 hh[4][2][4];
#pragma unroll
  for (int g = 0; g < 4; g++)
#pragma unroll
    for (int ct = 0; ct < 2; ct++) {
#pragma unroll
      for (int r = 0; r < 4; r++) hh[g][ct][r] = f2bf(acc[g][ct][r]);
      ushort4 st;
      st.x = hh[g][ct][0];
      st.y = hh[g][ct][1];
      st.z = hh[g][ct][2];
      st.w = hh[g][ct][3];
      const size_t P = (size_t)bid * 256 + wv * 64 + g * 16 + n;
      *(ushort4*)(a1ch + P * 32 + ct * 16 + q * 4) = st;
    }

#pragma unroll
  for (int ct = 0; ct < 2; ct++)
#pragma unroll
    for (int r = 0; r < 4; r++) {
      float v0 = bf2f(hh[0][ct][r]), v1 = bf2f(hh[1][ct][r]);
      float v2 = bf2f(hh[2][ct][r]), v3 = bf2f(hh[3][ct][r]);
      float s = v0 + v1 + v2 + v3;
      float qq = v0 * v0 + v1 * v1 + v2 * v2 + v3 * v3;
      s += __shfl_xor(s, 1); qq += __shfl_xor(qq, 1);
      s += __shfl_xor(s, 2); qq += __shfl_xor(qq, 2);
      s += __shfl_xor(s, 4); qq += __shfl_xor(qq, 4);
      s += __shfl_xor(s, 8); qq += __shfl_xor(qq, 8);
      if (n == 0) {
        int co = ct * 16 + q * 4 + r;
        ls[wv * 32 + co] = s;
        lq[wv * 32 + co] = qq;
      }
    }
  __syncthreads();
  if (threadIdx.x < 32) {
    int c = threadIdx.x;
    float s = ls[c] + ls[32 + c] + ls[64 + c] + ls[96 + c];
    float qq = lq[c] + lq[32 + c] + lq[64 + c] + lq[96 + c];
    atomicAdd(&S[c * D + d], s);
    atomicAdd(&S[1024 + c * D + d], qq);
  }
}

__global__ __launch_bounds__(256) void bn1_scale_kernel(float* __restrict__ S,
                                                        const float* __restrict__ g1f,
                                                        const float* __restrict__ b1f) {
  int cd = blockIdx.x * 256 + threadIdx.x;
  if (cd >= 1024) return;
  int c = cd / D;
  float mean = S[cd] / (float)HW;
  float var = S[1024 + cd] / (float)HW - mean * mean;
  float sc = g1f[c] * rsqrtf(var + EPS);
  S[cd] = sc;
  S[1024 + cd] = b1f[c] - mean * sc;
}

__global__ __launch_bounds__(256) void bn1_apply_ch_kernel(u16* __restrict__ a1ch,
                                                           const float* __restrict__ S) {
  __shared__ float sc[32], of[32];
  const int b = blockIdx.x;
  const int d = b / (HW / 256);
  if (threadIdx.x < 32) {
    sc[threadIdx.x] = S[threadIdx.x * D + d];
    of[threadIdx.x] = S[1024 + threadIdx.x * D + d];
  }
  __syncthreads();
  const size_t pb = ((size_t)b * 256 + threadIdx.x) * 32;
#pragma unroll
  for (int k = 0; k < 4; k++) {
    uint4 u = *(const uint4*)(a1ch + pb + 8 * k);
    unsigned w[4] = {u.x, u.y, u.z, u.w};
    unsigned ov[4];
#pragma unroll
    for (int m = 0; m < 4; m++) {
      int c0 = k * 8 + m * 2;
      float lo = bf2f((u16)(w[m] & 0xffffu));
      float hi = bf2f((u16)(w[m] >> 16));
      lo = fmaxf(lo * sc[c0] + of[c0], 0.f);
      hi = fmaxf(hi * sc[c0 + 1] + of[c0 + 1], 0.f);
      ov[m] = (unsigned)f2bf(lo) | ((unsigned)f2bf(hi) << 16);
    }
    uint4 o;
    o.x = ov[0]; o.y = ov[1]; o.z = ov[2]; o.w = ov[3];
    *(uint4*)(a1ch + pb + 8 * k) = o;
  }
}

// legacy core for the two-pass fallback path (unchanged, proven)
static __device__ __forceinline__ void conv_core_lds(const bf16x8* __restrict__ a1v,
                                                     const bf16x8* __restrict__ xv16,
                                                     const bf16x8* __restrict__ w2s,  // LDS
                                                     const bf16x8* __restrict__ wdv,
                                                     int d, int y, int xn, int q, int l,
                                                     f32x4& A0, f32x4& A1, f32x4& B0, f32x4& B1) {
  const bf16x8 zero = {0, 0, 0, 0, 0, 0, 0, 0};
  const bool qlo = (q < 2);
#pragma unroll
  for (int kd = 0; kd < 3; kd++) {
    int dd = d - 1 + kd;
    if ((unsigned)dd >= (unsigned)D) continue;
#pragma unroll
    for (int ky = 0; ky < 3; ky++) {
      int yy = y - 1 + ky;
      if ((unsigned)yy >= (unsigned)H) continue;
      const int rowb = dd * HW + yy * W;
#pragma unroll
      for (int kx = 0; kx < 3; kx++) {
        int xx = xn - 1 + kx;
        bool ok = (unsigned)xx < (unsigned)W;
        int xc = min(max(xx, 0), W - 1);
        int pi = rowb + xc;
        bf16x8 bm = a1v[pi * 4 + q];
        bf16x8 bx = qlo ? xv16[pi * 2 + q] : zero;
        if (!ok) { bm = zero; bx = zero; }
        const int tb = (kd * 9 + ky * 3 + kx) * 2;
        bf16x8 am0 = w2s[(tb + 0) * 64 + l];
        bf16x8 am1 = w2s[(tb + 1) * 64 + l];
        bf16x8 ad0 = qlo ? wdv[(tb + 0) * 64 + l] : zero;
        bf16x8 ad1 = qlo ? wdv[(tb + 1) * 64 + l] : zero;
        A0 = __builtin_amdgcn_mfma_f32_16x16x32_bf16(am0, bm, A0, 0, 0, 0);
        A1 = __builtin_amdgcn_mfma_f32_16x16x32_bf16(am1, bm, A1, 0, 0, 0);
        B0 = __builtin_amdgcn_mfma_f32_16x16x32_bf16(ad0, bx, B0, 0, 0, 0);
        B1 = __builtin_amdgcn_mfma_f32_16x16x32_bf16(ad1, bx, B1, 0, 0, 0);
      }
    }
  }
}

#define STATS_RED(ACC, BASE)                                                          \
  {                                                                                   \
    _Pragma("unroll") for (int r = 0; r < 4; r++) {                                   \
      float v = ACC[r];                                                               \
      float s = v, qq = v * v;                                                        \
      s += __shfl_xor(s, 1); qq += __shfl_xor(qq, 1);                                 \
      s += __shfl_xor(s, 2); qq += __shfl_xor(qq, 2);                                 \
      s += __shfl_xor(s, 4); qq += __shfl_xor(qq, 4);                                 \
      s += __shfl_xor(s, 8); qq += __shfl_xor(qq, 8);                                 \
      if (n == 0) {                                                                   \
        int ci = (BASE) + q * 4 + r;                                                  \
        ls[wv * 64 + ci] = s;                                                         \
        lq[wv * 64 + ci] = qq;                                                        \
      }                                                                               \
    }                                                                                 \
  }

#define STATS_RED2(Aa, Ab, BASE)                                                      \
  {                                                                                   \
    _Pragma("unroll") for (int r = 0; r < 4; r++) {                                   \
      float v0 = Aa[r], v1 = Ab[r];                                                   \
      float s = v0 + v1, qq = v0 * v0 + v1 * v1;                                      \
      s += __shfl_xor(s, 1); qq += __shfl_xor(qq, 1);                                 \
      s += __shfl_xor(s, 2); qq += __shfl_xor(qq, 2);                                 \
      s += __shfl_xor(s, 4); qq += __shfl_xor(qq, 4);                                 \
      s += __shfl_xor(s, 8); qq += __shfl_xor(qq, 8);                                 \
      if (n == 0) {                                                                   \
        int ci = (BASE) + q * 4 + r;                                                  \
        ls[wv * 64 + ci] = s;                                                         \
        lq[wv * 64 + ci] = qq;                                                        \
      }                                                                               \
    }                                                                                 \
  }

// store-once v3 (proven R9): 32 pixels (2 groups) per wave.
__global__ __launch_bounds__(1024) void conv_mfma_store_kernel(const u16* __restrict__ a1ch,
                                                               const u16* __restrict__ xch16,
                                                               const u16* __restrict__ w2f,
                                                               const u16* __restrict__ wdf,
                                                               float* __restrict__ A,
                                                               float* __restrict__ Bb,
                                                               float* __restrict__ S) {
  __shared__ u16 w2s[27648];  // 55296 B
  __shared__ float ls[16 * 64], lq[16 * 64];
  {
    const uint4* src = (const uint4*)w2f;
    uint4* dst = (uint4*)w2s;
    for (int i = threadIdx.x; i < 3456; i += 1024) dst[i] = src[i];
  }
  __syncthreads();

  const int hw = blockIdx.x;                 // grid = 1280, %8 == 0
  const int bid = (hw & 7) * 160 + (hw >> 3);
  const int t = threadIdx.x;
  const int l = t & 63, wv = t >> 6;
  const int n = l & 15, q = l >> 4;
  const int P0 = bid * 512 + wv * 32;        // 2 groups: P0, P0+16 (same d)
  const int d = P0 / HW;
  const int rp0 = P0 % HW;
  const int y0 = rp0 / W, x0 = rp0 % W;
  const int rp1 = (P0 + 16) % HW;
  const int y1g = rp1 / W, x1g = rp1 % W;

  const bf16x8 zero = {0, 0, 0, 0, 0, 0, 0, 0};
  const bool qlo = (q < 2);
  const bf16x8* a1v = (const bf16x8*)a1ch;
  const bf16x8* xv16 = (const bf16x8*)xch16;
  const bf16x8* w2v = (const bf16x8*)w2s;
  const bf16x8* wdv = (const bf16x8*)wdf;

  f32x4 aA0[2], aA1[2], aB0[2], aB1[2];
#pragma unroll
  for (int g = 0; g < 2; g++) {
    aA0[g] = (f32x4){0.f, 0.f, 0.f, 0.f};
    aA1[g] = (f32x4){0.f, 0.f, 0.f, 0.f};
    aB0[g] = (f32x4){0.f, 0.f, 0.f, 0.f};
    aB1[g] = (f32x4){0.f, 0.f, 0.f, 0.f};
  }

#pragma unroll
  for (int kd = 0; kd < 3; kd++) {
    int dd = d - 1 + kd;
    if ((unsigned)dd >= (unsigned)D) continue;
#pragma unroll
    for (int ky = 0; ky < 3; ky++) {
      int yy0 = y0 - 1 + ky, yy1 = y1g - 1 + ky;
      bool yok0 = (unsigned)yy0 < (unsigned)H, yok1 = (unsigned)yy1 < (unsigned)H;
      int rb0 = dd * HW + min(max(yy0, 0), H - 1) * W;
      int rb1 = dd * HW + min(max(yy1, 0), H - 1) * W;
#pragma unroll
      for (int kx = 0; kx < 3; kx++) {
        const int tb = (kd * 9 + ky * 3 + kx) * 2;
        bf16x8 am0 = w2v[(tb + 0) * 64 + l];
        bf16x8 am1 = w2v[(tb + 1) * 64 + l];
        bf16x8 ad0 = qlo ? wdv[(tb + 0) * 64 + l] : zero;
        bf16x8 ad1 = qlo ? wdv[(tb + 1) * 64 + l] : zero;
        {  // group 0
          int xx = x0 + n - 1 + kx;
          bool ok = yok0 && (unsigned)xx < (unsigned)W;
          int pi = rb0 + min(max(xx, 0), W - 1);
          bf16x8 bm = a1v[pi * 4 + q];
          bf16x8 bx = qlo ? xv16[pi * 2 + q] : zero;
          if (!ok) { bm = zero; bx = zero; }
          aA0[0] = __builtin_amdgcn_mfma_f32_16x16x32_bf16(am0, bm, aA0[0], 0, 0, 0);
          aA1[0] = __builtin_amdgcn_mfma_f32_16x16x32_bf16(am1, bm, aA1[0], 0, 0, 0);
          aB0[0] = __builtin_amdgcn_mfma_f32_16x16x32_bf16(ad0, bx, aB0[0], 0, 0, 0);
          aB1[0] = __builtin_amdgcn_mfma_f32_16x16x32_bf16(ad1, bx, aB1[0], 0, 0, 0);
        }
        {  // group 1
          int xx = x1g + n - 1 + kx;
          bool ok = yok1 && (unsigned)xx < (unsigned)W;
          int pi = rb1 + min(max(xx, 0), W - 1);
          bf16x8 bm = a1v[pi * 4 + q];
          bf16x8 bx = qlo ? xv16[pi * 2 + q] : zero;
          if (!ok) { bm = zero; bx = zero; }
          aA0[1] = __builtin_amdgcn_mfma_f32_16x16x32_bf16(am0, bm, aA0[1], 0, 0, 0);
          aA1[1] = __builtin_amdgcn_mfma_f32_16x16x32_bf16(am1, bm, aA1[1], 0, 0, 0);
          aB0[1] = __builtin_amdgcn_mfma_f32_16x16x32_bf16(ad0, bx, aB0[1], 0, 0, 0);
          aB1[1] = __builtin_amdgcn_mfma_f32_16x16x32_bf16(ad1, bx, aB1[1], 0, 0, 0);
        }
      }
    }
  }

#pragma unroll
  for (int g = 0; g < 2; g++) {
    const int Pg = P0 + 16 * g;
#pragma unroll
    for (int r = 0; r < 4; r++) {
      int co = q * 4 + r;
      A[co * DHW + Pg + n] = aA0[g][r];
      A[(co + 16) * DHW + Pg + n] = aA1[g][r];
      Bb[co * DHW + Pg + n] = aB0[g][r];
      Bb[(co + 16) * DHW + Pg + n] = aB1[g][r];
    }
  }

  STATS_RED2(aA0[0], aA0[1], 0)
  STATS_RED2(aA1[0], aA1[1], 16)
  STATS_RED2(aB0[0], aB0[1], 32)
  STATS_RED2(aB1[0], aB1[1], 48)
  __syncthreads();
  if (t < 64) {
    float s = 0.f, qq = 0.f;
    for (int w = 0; w < 16; w++) { s += ls[w * 64 + t]; qq += lq[w * 64 + t]; }
    if (t < 32) {
      atomicAdd(&S[2048 + t], s);
      atomicAdd(&S[2080 + t], qq);
    } else {
      atomicAdd(&S[2112 + t - 32], s);
      atomicAdd(&S[2144 + t - 32], qq);
    }
  }
}

// two-pass fallback: stats only (proven)
__global__ __launch_bounds__(1024) void conv_mfma_stats_kernel(const u16* __restrict__ a1ch,
                                                               const u16* __restrict__ xch16,
                                                               const u16* __restrict__ w2f,
                                                               const u16* __restrict__ wdf,
                                                               float* __restrict__ S) {
  __shared__ u16 w2s[27648];
  __shared__ float ls[16 * 64], lq[16 * 64];
  {
    const uint4* src = (const uint4*)w2f;
    uint4* dst = (uint4*)w2s;
    for (int i = threadIdx.x; i < 3456; i += 1024) dst[i] = src[i];
  }
  __syncthreads();

  const int hw = blockIdx.x;
  const int bid = (hw & 7) * 320 + (hw >> 3);
  const int t = threadIdx.x;
  const int l = t & 63, wv = t >> 6;
  const int n = l & 15, q = l >> 4;
  const int P = bid * 256 + wv * 16;
  const int d = P / HW;
  const int rp = P % HW;
  const int y = rp / W, xc0 = rp % W;

  f32x4 A0 = {0.f, 0.f, 0.f, 0.f}, A1 = {0.f, 0.f, 0.f, 0.f};
  f32x4 B0 = {0.f, 0.f, 0.f, 0.f}, B1 = {0.f, 0.f, 0.f, 0.f};
  conv_core_lds((const bf16x8*)a1ch, (const bf16x8*)xch16, (const bf16x8*)w2s,
                (const bf16x8*)wdf, d, y, xc0 + n, q, l, A0, A1, B0, B1);

  STATS_RED(A0, 0)
  STATS_RED(A1, 16)
  STATS_RED(B0, 32)
  STATS_RED(B1, 48)
  __syncthreads();
  if (t < 64) {
    float s = 0.f, qq = 0.f;
    for (int w = 0; w < 16; w++) { s += ls[w * 64 + t]; qq += lq[w * 64 + t]; }
    if (t < 32) {
      atomicAdd(&S[2048 + t], s);
      atomicAdd(&S[2080 + t], qq);
    } else {
      atomicAdd(&S[2112 + t - 32], s);
      atomicAdd(&S[2144 + t - 32], qq);
    }
  }
}

__global__ void bn3_final_kernel(float* __restrict__ S, const float* __restrict__ g2f,
                                 const float* __restrict__ b2f, const float* __restrict__ gdf,
                                 const float* __restrict__ bdf) {
  int t = threadIdx.x;  // 64 threads
  if (t < 32) {
    float mean = S[2048 + t] / (float)DHW;
    float var = S[2080 + t] / (float)DHW - mean * mean;
    float sc = g2f[t] * rsqrtf(var + EPS);
    S[2176 + t] = sc;
    S[2208 + t] = b2f[t] - mean * sc;
  } else {
    int c = t - 32;
    float mean = S[2112 + c] / (float)DHW;
    float var = S[2144 + c] / (float)DHW - mean * mean;
    float sc = gdf[c] * rsqrtf(var + EPS);
    S[2240 + c] = sc;
    S[2272 + c] = bdf[c] - mean * sc;
  }
}

// store path: elementwise combine, fp32 inputs
__global__ __launch_bounds__(256) void combine32_kernel(const float* __restrict__ A,
                                                        const float* __restrict__ Bb,
                                                        const float* __restrict__ S,
                                                        const int* __restrict__ flagp,
                                                        void* __restrict__ out) {
  int i = (blockIdx.x * 256 + threadIdx.x) * 4;
  int co = i / DHW;
  float s2 = S[2176 + co], o2 = S[2208 + co];
  float sd = S[2240 + co], od = S[2272 + co];
  float4 va = *(const float4*)(A + i);
  float4 vb = *(const float4*)(Bb + i);
  float r0 = fmaxf(va.x * s2 + o2 + vb.x * sd + od, 0.f);
  float r1 = fmaxf(va.y * s2 + o2 + vb.y * sd + od, 0.f);
  float r2 = fmaxf(va.z * s2 + o2 + vb.z * sd + od, 0.f);
  float r3 = fmaxf(va.w * s2 + o2 + vb.w * sd + od, 0.f);
  int bf = flagp[0];
  if (bf) {
    ushort4 st;
    st.x = f2bf(r0); st.y = f2bf(r1); st.z = f2bf(r2); st.w = f2bf(r3);
    *(ushort4*)((u16*)out + i) = st;
  } else {
    float4 st;
    st.x = r0; st.y = r1; st.z = r2; st.w = r3;
    *(float4*)((float*)out + i) = st;
  }
}

// two-pass fallback: recompute convs, fuse BN3 + add + relu (proven)
__global__ __launch_bounds__(256) void conv_mfma_final_kernel(const u16* __restrict__ a1ch,
                                                              const u16* __restrict__ xch16,
                                                              const u16* __restrict__ w2f,
                                                              const u16* __restrict__ wdf,
                                                              const float* __restrict__ S,
                                                              const int* __restrict__ flagp,
                                                              void* __restrict__ out) {
  __shared__ u16 w2s[27648];
  {
    const uint4* src = (const uint4*)w2f;
    uint4* dst = (uint4*)w2s;
    for (int i = threadIdx.x; i < 3456; i += 256) dst[i] = src[i];
  }
  __syncthreads();

  const int hw = blockIdx.x;                   // grid = 10240
  const int bid = (hw & 7) * 1280 + (hw >> 3);
  const int t = threadIdx.x;
  const int l = t & 63, wv = t >> 6;
  const int n = l & 15, q = l >> 4;
  const int P = bid * 64 + wv * 16;
  const int d = P / HW;
  const int rp = P % HW;
  const int y = rp / W, xc0 = rp % W;

  f32x4 A0 = {0.f, 0.f, 0.f, 0.f}, A1 = {0.f, 0.f, 0.f, 0.f};
  f32x4 B0 = {0.f, 0.f, 0.f, 0.f}, B1 = {0.f, 0.f, 0.f, 0.f};
  conv_core_lds((const bf16x8*)a1ch, (const bf16x8*)xch16, (const bf16x8*)w2s,
                (const bf16x8*)wdf, d, y, xc0 + n, q, l, A0, A1, B0, B1);

  const int bf = flagp[0];
#pragma unroll
  for (int r = 0; r < 4; r++) {
    int co = q * 4 + r;
    {
      float s2 = S[2176 + co], o2 = S[2208 + co];
      float sd = S[2240 + co], od = S[2272 + co];
      float v = fmaxf(A0[r] * s2 + o2 + B0[r] * sd + od, 0.f);
      int ai = co * DHW + P + n;
      if (bf) ((u16*)out)[ai] = f2bf(v);
      else ((float*)out)[ai] = v;
    }
    {
      int c2 = co + 16;
      float s2 = S[2176 + c2], o2 = S[2208 + c2];
      float sd = S[2240 + c2], od = S[2272 + c2];
      float v = fmaxf(A1[r] * s2 + o2 + B1[r] * sd + od, 0.f);
      int ai = c2 * DHW + P + n;
      if (bf) ((u16*)out)[ai] = f2bf(v);
      else ((float*)out)[ai] = v;
    }
  }
}

extern "C" void kernel_launch(void* const* d_in, const int* in_sizes, int n_in,
                              void* d_out, int out_size, void* d_ws, size_t ws_size,
                              hipStream_t stream) {
  const void* x = d_in[0];
  const void* f = d_in[1];

  char* ws = (char*)d_ws;
  float* S = (float*)ws;
  int* flag = (int*)ws + FLAG_SLOT;
  float* WF = (float*)(ws + WF_OFF);
  u16* dfrag = (u16*)(ws + DFRAG_OFF);
  u16* a1ch = (u16*)(ws + A1CH_OFF);
  u16* xch16 = (u16*)(ws + XCH16_OFF);

  zero_kernel<<<16, 256, 0, stream>>>(S);
  sniff_kernel<<<1, 256, 0, stream>>>((const u16*)x, flag);

  // inputs: x,f,w_off,w_reg,g1,b1,w2,g2,b2,wd,gd,bd
  cvt_all_kernel<<<191, 256, 0, stream>>>(d_in[2], d_in[3], d_in[6], d_in[9], d_in[4], d_in[5],
                                          d_in[7], d_in[8], d_in[10], d_in[11], WF, flag);

  const int store = (ws_size >= NEED_STORE) ? 1 : 0;
  u16* w2frag = (u16*)(ws + (store ? FRAGS_W2 : FRAG2P_W2));
  u16* wdfrag = (u16*)(ws + (store ? FRAGS_WD : FRAG2P_WD));

  prep_kernel<<<247, 256, 0, stream>>>(WF, WF + WOFFT_O, w2frag, wdfrag, dfrag);
  chpose_kernel<<<DHW / 256, 256, 0, stream>>>(x, xch16, flag);

  deform_mfma_kernel<<<2560, 256, 0, stream>>>(x, f, WF + WOFFT_O, dfrag, a1ch, flag, S);
  bn1_scale_kernel<<<4, 256, 0, stream>>>(S, WF + G1_O, WF + B1_O);
  bn1_apply_ch_kernel<<<DHW / 256, 256, 0, stream>>>(a1ch, S);

  if (store) {
    float* A = (float*)(ws + STA_OFF);
    float* Bb = (float*)(ws + STB_OFF);
    conv_mfma_store_kernel<<<1280, 1024, 0, stream>>>(a1ch, xch16, w2frag, wdfrag, A, Bb, S);
    bn3_final_kernel<<<1, 64, 0, stream>>>(S, WF + G2_O, WF + B2_O, WF + GD_O, WF + BD_O);
    combine32_kernel<<<NOUT / 1024, 256, 0, stream>>>(A, Bb, S, flag, d_out);
  } else {
    conv_mfma_stats_kernel<<<2560, 1024, 0, stream>>>(a1ch, xch16, w2frag, wdfrag, S);
    bn3_final_kernel<<<1, 64, 0, stream>>>(S, WF + G2_O, WF + B2_O, WF + GD_O, WF + BD_O);
    conv_mfma_final_kernel<<<10240, 256, 0, stream>>>(a1ch, xch16, w2frag, wdfrag, S, flag,
                                                      d_out);
  }
}

// Round 12
// 709.176 us; speedup vs baseline: 1.1286x; 1.1286x over previous
//
#include <hip/hip_runtime.h>

using u16 = unsigned short;

constexpr int CIN = 16, COUT = 32, COFF = 16;
constexpr int D = 32, H = 128, W = 160;
constexpr int HW = H * W;         // 20480
constexpr int DHW = D * HW;       // 655360
constexpr int NOUT = COUT * DHW;  // 20971520
constexpr float EPS = 1e-5f;

// ---- workspace layout (byte offsets) ----
constexpr size_t WF_OFF = 16384;
constexpr size_t A1CH_OFF = 262144;        // a1ch [pix][32ch] bf16: 41,943,040
constexpr size_t XCH16_OFF = 42205184;     // xch16 [pix][16ch] bf16: 20,971,520
constexpr size_t FRAG2P_W2 = 84148224;     // frag slots, two-pass path
constexpr size_t FRAG2P_WD = 84203520;
constexpr size_t NEED_2PASS = 84258816;
constexpr size_t STA_OFF = 63176704;       // fp32 A
constexpr size_t STB_OFF = 147062784;      // fp32 B
constexpr size_t FRAGS_W2 = 230948864;     // frag slots, store path (after B)
constexpr size_t FRAGS_WD = 231004160;
constexpr size_t NEED_STORE = 231059456;
// WF float-offsets
constexpr int WOFF_O = 0, WREG_O = 2592, W2_O = 7200, WD_O = 34848;
constexpr int G1_O = 48672, B1_O = 48704, G2_O = 48736, B2_O = 48768, GD_O = 48800, BD_O = 48832;
constexpr int WOFFT_O = 49152, WREGT_O = 52224;  // transposed weights (ends 56832, fits)
constexpr int FLAG_SLOT = 3000;

typedef short bf16x8 __attribute__((ext_vector_type(8)));
typedef float f32x4 __attribute__((ext_vector_type(4)));
typedef u16 u16x8 __attribute__((ext_vector_type(8)));

static __device__ __forceinline__ float bf2f(u16 h) {
  unsigned u = ((unsigned)h) << 16;
  float f;
  __builtin_memcpy(&f, &u, 4);
  return f;
}
static __device__ __forceinline__ u16 f2bf(float f) {
  unsigned u;
  __builtin_memcpy(&u, &f, 4);
  u += 0x7fffu + ((u >> 16) & 1u);
  return (u16)(u >> 16);
}
static __device__ __forceinline__ float ldin(const void* p, int i, int bf) {
  float r;
  if (bf) r = bf2f(((const u16*)p)[i]);
  else r = ((const float*)p)[i];
  return r;
}

__global__ __launch_bounds__(256) void zero_kernel(float* __restrict__ S) {
  S[blockIdx.x * 256 + threadIdx.x] = 0.f;
}

__global__ __launch_bounds__(256) void sniff_kernel(const u16* __restrict__ x,
                                                    int* __restrict__ flag) {
  __shared__ int sh[256];
  int cnt = 0;
  for (int i = threadIdx.x; i < 4096; i += 256) {
    int e = (x[i] >> 7) & 0xff;
    cnt += (e >= 96 && e <= 144) ? 1 : 0;
  }
  sh[threadIdx.x] = cnt;
  __syncthreads();
  for (int s = 128; s > 0; s >>= 1) {
    if (threadIdx.x < (unsigned)s) sh[threadIdx.x] += sh[threadIdx.x + s];
    __syncthreads();
  }
  if (threadIdx.x == 0) flag[0] = (sh[0] > 3072) ? 1 : 0;
}

// all 10 input conversions in one launch
__global__ __launch_bounds__(256) void cvt_all_kernel(
    const void* s0, const void* s1, const void* s2, const void* s3, const void* s4,
    const void* s5, const void* s6, const void* s7, const void* s8, const void* s9,
    float* __restrict__ WF, const int* __restrict__ flagp) {
  const int bf = flagp[0];
  int i = blockIdx.x * 256 + threadIdx.x;
  if (i < 2592) { WF[WOFF_O + i] = ldin(s0, i, bf); return; }
  i -= 2592;
  if (i < 4608) { WF[WREG_O + i] = ldin(s1, i, bf); return; }
  i -= 4608;
  if (i < 27648) { WF[W2_O + i] = ldin(s2, i, bf); return; }
  i -= 27648;
  if (i < 13824) { WF[WD_O + i] = ldin(s3, i, bf); return; }
  i -= 13824;
  if (i < 32) { WF[G1_O + i] = ldin(s4, i, bf); return; }
  i -= 32;
  if (i < 32) { WF[B1_O + i] = ldin(s5, i, bf); return; }
  i -= 32;
  if (i < 32) { WF[G2_O + i] = ldin(s6, i, bf); return; }
  i -= 32;
  if (i < 32) { WF[B2_O + i] = ldin(s7, i, bf); return; }
  i -= 32;
  if (i < 32) { WF[GD_O + i] = ldin(s8, i, bf); return; }
  i -= 32;
  if (i < 32) { WF[BD_O + i] = ldin(s9, i, bf); }
}

// all weight reshapes/packs in one launch (depends on cvt_all output)
__global__ __launch_bounds__(256) void prep_kernel(const float* __restrict__ WF,
                                                   float* __restrict__ wofft,
                                                   float* __restrict__ wregt,
                                                   u16* __restrict__ w2frag,
                                                   u16* __restrict__ wdfrag) {
  int i = blockIdx.x * 256 + threadIdx.x;
  if (i < 2592) {  // w_off [18][144] -> [144][18]
    int ch = i / 144, widx = i % 144;
    wofft[widx * 18 + ch] = WF[WOFF_O + i];
    return;
  }
  i -= 2592;
  if (i < 4608) {  // w_reg [32][144] -> [144][32]
    int co = i / 144, k = i % 144;
    wregt[k * 32 + co] = WF[WREG_O + i];
    return;
  }
  i -= 4608;
  if (i < 27648) {  // pack w2 frags (nci=32)
    int j = i & 7, l = (i >> 3) & 63, cotile = (i >> 9) & 1, tap = i >> 10;
    int co = cotile * 16 + (l & 15);
    int k = (l >> 4) * 8 + j;
    w2frag[i] = f2bf(WF[W2_O + (co * 32 + k) * 27 + tap]);
    return;
  }
  i -= 27648;
  if (i < 27648) {  // pack wd frags (nci=16, zero-pad k>=16)
    int j = i & 7, l = (i >> 3) & 63, cotile = (i >> 9) & 1, tap = i >> 10;
    int co = cotile * 16 + (l & 15);
    int k = (l >> 4) * 8 + j;
    float v = (k < 16) ? WF[WD_O + (co * 16 + k) * 27 + tap] : 0.f;
    wdfrag[i] = f2bf(v);
  }
}

// transpose 16-channel channel-major input -> [pix][16ch] bf16 (32 B/pixel)
__global__ __launch_bounds__(256) void chpose_kernel(const void* __restrict__ src,
                                                     u16* __restrict__ dst,
                                                     const int* __restrict__ flagp) {
  const int bf = flagp[0];
  __shared__ u16 lt[16][258];
  const int base = blockIdx.x * 256;
  const int t = threadIdx.x;
#pragma unroll
  for (int ci = 0; ci < 16; ci++) lt[ci][t] = f2bf(ldin(src, ci * DHW + base + t, bf));
  __syncthreads();
  const size_t pb = (size_t)(base + t) * 16;
  uint4 u0, u1;
  u0.x = (unsigned)lt[0][t] | ((unsigned)lt[1][t] << 16);
  u0.y = (unsigned)lt[2][t] | ((unsigned)lt[3][t] << 16);
  u0.z = (unsigned)lt[4][t] | ((unsigned)lt[5][t] << 16);
  u0.w = (unsigned)lt[6][t] | ((unsigned)lt[7][t] << 16);
  u1.x = (unsigned)lt[8][t] | ((unsigned)lt[9][t] << 16);
  u1.y = (unsigned)lt[10][t] | ((unsigned)lt[11][t] << 16);
  u1.z = (unsigned)lt[12][t] | ((unsigned)lt[13][t] << 16);
  u1.w = (unsigned)lt[14][t] | ((unsigned)lt[15][t] << 16);
  *(uint4*)(dst + pb) = u0;
  *(uint4*)(dst + pb + 8) = u1;
}

// Deformable conv (proven R9 structure): channel-major coalesced loads +
// XCD swizzle + transposed weights + channels-last bf16 output + BN1 stats.
__global__ __launch_bounds__(256) void deform_chm_kernel(const void* __restrict__ x,
                                                         const void* __restrict__ f,
                                                         const float* __restrict__ w_off_t,
                                                         const float* __restrict__ w_reg_t,
                                                         u16* __restrict__ a1ch,
                                                         const int* __restrict__ flagp,
                                                         float* __restrict__ S) {
  const int bf = flagp[0];
  const int hw = blockIdx.x;                 // grid = 2560, %8 == 0
  const int bid = (hw & 7) * 320 + (hw >> 3);
  const int d = bid / 80;
  const int p = (bid % 80) * 256 + threadIdx.x;
  const int y = p / W;
  const int xx = p % W;
  const int dbase = d * HW;

  float doff[18];
#pragma unroll
  for (int t = 0; t < 18; t++) doff[t] = 0.f;
  for (int ci = 0; ci < COFF; ci++) {
    const int fbase = ci * DHW + dbase;
#pragma unroll
    for (int ki = 0; ki < 3; ki++) {
      int yy = y - 1 + ki;
      bool yok = (unsigned)yy < (unsigned)H;
#pragma unroll
      for (int kj = 0; kj < 3; kj++) {
        int xj = xx - 1 + kj;
        float v = (yok && (unsigned)xj < (unsigned)W) ? ldin(f, fbase + yy * W + xj, bf) : 0.f;
        int widx = ci * 9 + ki * 3 + kj;
#pragma unroll
        for (int t = 0; t < 18; t++) doff[t] += v * w_off_t[widx * 18 + t];
      }
    }
  }

  float acc[COUT];
#pragma unroll
  for (int co = 0; co < COUT; co++) acc[co] = 0.f;

#pragma unroll
  for (int t = 0; t < 9; t++) {
    float dy = fminf(fmaxf(doff[2 * t], -1.f), 1.f);
    float dx = fminf(fmaxf(doff[2 * t + 1], -1.f), 1.f);
    float py = (float)(y - 1 + t / 3) + dy;
    float px = (float)(xx - 1 + t % 3) + dx;
    float y0f = floorf(py), x0f = floorf(px);
    float wy1 = py - y0f, wx1 = px - x0f;
    int y0 = (int)y0f, x0i = (int)x0f;
    int y1 = y0 + 1, x1 = x0i + 1;
    bool y0v = (unsigned)y0 < (unsigned)H, y1v = (unsigned)y1 < (unsigned)H;
    bool x0v = (unsigned)x0i < (unsigned)W, x1v = (unsigned)x1 < (unsigned)W;
    float c00 = (y0v && x0v) ? (1.f - wy1) * (1.f - wx1) : 0.f;
    float c01 = (y0v && x1v) ? (1.f - wy1) * wx1 : 0.f;
    float c10 = (y1v && x0v) ? wy1 * (1.f - wx1) : 0.f;
    float c11 = (y1v && x1v) ? wy1 * wx1 : 0.f;
    int y0c = min(max(y0, 0), H - 1) * W, y1c = min(max(y1, 0), H - 1) * W;
    int x0c = min(max(x0i, 0), W - 1), x1c = min(max(x1, 0), W - 1);

    for (int ci = 0; ci < CIN; ci++) {
      const int xbase = ci * DHW + dbase;
      float s = c00 * ldin(x, xbase + y0c + x0c, bf) + c01 * ldin(x, xbase + y0c + x1c, bf) +
                c10 * ldin(x, xbase + y1c + x0c, bf) + c11 * ldin(x, xbase + y1c + x1c, bf);
      const float* wp = w_reg_t + (ci * 9 + t) * 32;
#pragma unroll
      for (int co = 0; co < COUT; co++) acc[co] += s * wp[co];
    }
  }

  // store channels-last bf16
  u16 hh[COUT];
#pragma unroll
  for (int co = 0; co < COUT; co++) hh[co] = f2bf(acc[co]);
  const size_t pb = ((size_t)dbase + p) * 32;
#pragma unroll
  for (int k = 0; k < 4; k++) {
    uint4 u;
    u.x = (unsigned)hh[8 * k + 0] | ((unsigned)hh[8 * k + 1] << 16);
    u.y = (unsigned)hh[8 * k + 2] | ((unsigned)hh[8 * k + 3] << 16);
    u.z = (unsigned)hh[8 * k + 4] | ((unsigned)hh[8 * k + 5] << 16);
    u.w = (unsigned)hh[8 * k + 6] | ((unsigned)hh[8 * k + 7] << 16);
    *(uint4*)(a1ch + pb + 8 * k) = u;
  }

  // fused BN1 stats on bf16-rounded values
  const int l = threadIdx.x & 63;
  const int wv = threadIdx.x >> 6;
  __shared__ float ls[128], lq[128];
#pragma unroll
  for (int co = 0; co < COUT; co++) {
    float v = bf2f(hh[co]);
    float s = v, qq = v * v;
    s += __shfl_xor(s, 1);  qq += __shfl_xor(qq, 1);
    s += __shfl_xor(s, 2);  qq += __shfl_xor(qq, 2);
    s += __shfl_xor(s, 4);  qq += __shfl_xor(qq, 4);
    s += __shfl_xor(s, 8);  qq += __shfl_xor(qq, 8);
    s += __shfl_xor(s, 16); qq += __shfl_xor(qq, 16);
    s += __shfl_xor(s, 32); qq += __shfl_xor(qq, 32);
    if (l == 0) { ls[wv * 32 + co] = s; lq[wv * 32 + co] = qq; }
  }
  __syncthreads();
  if (threadIdx.x < 32) {
    int c = threadIdx.x;
    float s = ls[c] + ls[32 + c] + ls[64 + c] + ls[96 + c];
    float qq = lq[c] + lq[32 + c] + lq[64 + c] + lq[96 + c];
    atomicAdd(&S[c * D + d], s);
    atomicAdd(&S[1024 + c * D + d], qq);
  }
}

__global__ __launch_bounds__(256) void bn1_scale_kernel(float* __restrict__ S,
                                                        const float* __restrict__ g1f,
                                                        const float* __restrict__ b1f) {
  int cd = blockIdx.x * 256 + threadIdx.x;
  if (cd >= 1024) return;
  int c = cd / D;
  float mean = S[cd] / (float)HW;
  float var = S[1024 + cd] / (float)HW - mean * mean;
  float sc = g1f[c] * rsqrtf(var + EPS);
  S[cd] = sc;
  S[1024 + cd] = b1f[c] - mean * sc;
}

__global__ __launch_bounds__(256) void bn1_apply_ch_kernel(u16* __restrict__ a1ch,
                                                           const float* __restrict__ S) {
  __shared__ float sc[32], of[32];
  const int b = blockIdx.x;
  const int d = b / (HW / 256);
  if (threadIdx.x < 32) {
    sc[threadIdx.x] = S[threadIdx.x * D + d];
    of[threadIdx.x] = S[1024 + threadIdx.x * D + d];
  }
  __syncthreads();
  const size_t pb = ((size_t)b * 256 + threadIdx.x) * 32;
#pragma unroll
  for (int k = 0; k < 4; k++) {
    uint4 u = *(const uint4*)(a1ch + pb + 8 * k);
    unsigned w[4] = {u.x, u.y, u.z, u.w};
    unsigned ov[4];
#pragma unroll
    for (int m = 0; m < 4; m++) {
      int c0 = k * 8 + m * 2;
      float lo = bf2f((u16)(w[m] & 0xffffu));
      float hi = bf2f((u16)(w[m] >> 16));
      lo = fmaxf(lo * sc[c0] + of[c0], 0.f);
      hi = fmaxf(hi * sc[c0 + 1] + of[c0 + 1], 0.f);
      ov[m] = (unsigned)f2bf(lo) | ((unsigned)f2bf(hi) << 16);
    }
    uint4 o;
    o.x = ov[0]; o.y = ov[1]; o.z = ov[2]; o.w = ov[3];
    *(uint4*)(a1ch + pb + 8 * k) = o;
  }
}

// legacy core for the two-pass fallback path (unchanged, proven)
static __device__ __forceinline__ void conv_core_lds(const bf16x8* __restrict__ a1v,
                                                     const bf16x8* __restrict__ xv16,
                                                     const bf16x8* __restrict__ w2s,  // LDS
                                                     const bf16x8* __restrict__ wdv,
                                                     int d, int y, int xn, int q, int l,
                                                     f32x4& A0, f32x4& A1, f32x4& B0, f32x4& B1) {
  const bf16x8 zero = {0, 0, 0, 0, 0, 0, 0, 0};
  const bool qlo = (q < 2);
#pragma unroll
  for (int kd = 0; kd < 3; kd++) {
    int dd = d - 1 + kd;
    if ((unsigned)dd >= (unsigned)D) continue;
#pragma unroll
    for (int ky = 0; ky < 3; ky++) {
      int yy = y - 1 + ky;
      if ((unsigned)yy >= (unsigned)H) continue;
      const int rowb = dd * HW + yy * W;
#pragma unroll
      for (int kx = 0; kx < 3; kx++) {
        int xx = xn - 1 + kx;
        bool ok = (unsigned)xx < (unsigned)W;
        int xc = min(max(xx, 0), W - 1);
        int pi = rowb + xc;
        bf16x8 bm = a1v[pi * 4 + q];
        bf16x8 bx = qlo ? xv16[pi * 2 + q] : zero;
        if (!ok) { bm = zero; bx = zero; }
        const int tb = (kd * 9 + ky * 3 + kx) * 2;
        bf16x8 am0 = w2s[(tb + 0) * 64 + l];
        bf16x8 am1 = w2s[(tb + 1) * 64 + l];
        bf16x8 ad0 = qlo ? wdv[(tb + 0) * 64 + l] : zero;
        bf16x8 ad1 = qlo ? wdv[(tb + 1) * 64 + l] : zero;
        A0 = __builtin_amdgcn_mfma_f32_16x16x32_bf16(am0, bm, A0, 0, 0, 0);
        A1 = __builtin_amdgcn_mfma_f32_16x16x32_bf16(am1, bm, A1, 0, 0, 0);
        B0 = __builtin_amdgcn_mfma_f32_16x16x32_bf16(ad0, bx, B0, 0, 0, 0);
        B1 = __builtin_amdgcn_mfma_f32_16x16x32_bf16(ad1, bx, B1, 0, 0, 0);
      }
    }
  }
}

#define STATS_RED(ACC, BASE)                                                          \
  {                                                                                   \
    _Pragma("unroll") for (int r = 0; r < 4; r++) {                                   \
      float v = ACC[r];                                                               \
      float s = v, qq = v * v;                                                        \
      s += __shfl_xor(s, 1); qq += __shfl_xor(qq, 1);                                 \
      s += __shfl_xor(s, 2); qq += __shfl_xor(qq, 2);                                 \
      s += __shfl_xor(s, 4); qq += __shfl_xor(qq, 4);                                 \
      s += __shfl_xor(s, 8); qq += __shfl_xor(qq, 8);                                 \
      if (n == 0) {                                                                   \
        int ci = (BASE) + q * 4 + r;                                                  \
        ls[wv * 64 + ci] = s;                                                         \
        lq[wv * 64 + ci] = qq;                                                        \
      }                                                                               \
    }                                                                                 \
  }

#define STATS_RED2(Aa, Ab, BASE)                                                      \
  {                                                                                   \
    _Pragma("unroll") for (int r = 0; r < 4; r++) {                                   \
      float v0 = Aa[r], v1 = Ab[r];                                                   \
      float s = v0 + v1, qq = v0 * v0 + v1 * v1;                                      \
      s += __shfl_xor(s, 1); qq += __shfl_xor(qq, 1);                                 \
      s += __shfl_xor(s, 2); qq += __shfl_xor(qq, 2);                                 \
      s += __shfl_xor(s, 4); qq += __shfl_xor(qq, 4);                                 \
      s += __shfl_xor(s, 8); qq += __shfl_xor(qq, 8);                                 \
      if (n == 0) {                                                                   \
        int ci = (BASE) + q * 4 + r;                                                  \
        ls[wv * 64 + ci] = s;                                                         \
        lq[wv * 64 + ci] = qq;                                                        \
      }                                                                               \
    }                                                                                 \
  }

// store-once v3 (proven R9): 32 pixels (2 groups) per wave.
__global__ __launch_bounds__(1024) void conv_mfma_store_kernel(const u16* __restrict__ a1ch,
                                                               const u16* __restrict__ xch16,
                                                               const u16* __restrict__ w2f,
                                                               const u16* __restrict__ wdf,
                                                               float* __restrict__ A,
                                                               float* __restrict__ Bb,
                                                               float* __restrict__ S) {
  __shared__ u16 w2s[27648];  // 55296 B
  __shared__ float ls[16 * 64], lq[16 * 64];
  {
    const uint4* src = (const uint4*)w2f;
    uint4* dst = (uint4*)w2s;
    for (int i = threadIdx.x; i < 3456; i += 1024) dst[i] = src[i];
  }
  __syncthreads();

  const int hw = blockIdx.x;                 // grid = 1280, %8 == 0
  const int bid = (hw & 7) * 160 + (hw >> 3);
  const int t = threadIdx.x;
  const int l = t & 63, wv = t >> 6;
  const int n = l & 15, q = l >> 4;
  const int P0 = bid * 512 + wv * 32;        // 2 groups: P0, P0+16 (same d)
  const int d = P0 / HW;
  const int rp0 = P0 % HW;
  const int y0 = rp0 / W, x0 = rp0 % W;
  const int rp1 = (P0 + 16) % HW;
  const int y1g = rp1 / W, x1g = rp1 % W;

  const bf16x8 zero = {0, 0, 0, 0, 0, 0, 0, 0};
  const bool qlo = (q < 2);
  const bf16x8* a1v = (const bf16x8*)a1ch;
  const bf16x8* xv16 = (const bf16x8*)xch16;
  const bf16x8* w2v = (const bf16x8*)w2s;
  const bf16x8* wdv = (const bf16x8*)wdf;

  f32x4 aA0[2], aA1[2], aB0[2], aB1[2];
#pragma unroll
  for (int g = 0; g < 2; g++) {
    aA0[g] = (f32x4){0.f, 0.f, 0.f, 0.f};
    aA1[g] = (f32x4){0.f, 0.f, 0.f, 0.f};
    aB0[g] = (f32x4){0.f, 0.f, 0.f, 0.f};
    aB1[g] = (f32x4){0.f, 0.f, 0.f, 0.f};
  }

#pragma unroll
  for (int kd = 0; kd < 3; kd++) {
    int dd = d - 1 + kd;
    if ((unsigned)dd >= (unsigned)D) continue;
#pragma unroll
    for (int ky = 0; ky < 3; ky++) {
      int yy0 = y0 - 1 + ky, yy1 = y1g - 1 + ky;
      bool yok0 = (unsigned)yy0 < (unsigned)H, yok1 = (unsigned)yy1 < (unsigned)H;
      int rb0 = dd * HW + min(max(yy0, 0), H - 1) * W;
      int rb1 = dd * HW + min(max(yy1, 0), H - 1) * W;
#pragma unroll
      for (int kx = 0; kx < 3; kx++) {
        const int tb = (kd * 9 + ky * 3 + kx) * 2;
        bf16x8 am0 = w2v[(tb + 0) * 64 + l];
        bf16x8 am1 = w2v[(tb + 1) * 64 + l];
        bf16x8 ad0 = qlo ? wdv[(tb + 0) * 64 + l] : zero;
        bf16x8 ad1 = qlo ? wdv[(tb + 1) * 64 + l] : zero;
        {  // group 0
          int xx = x0 + n - 1 + kx;
          bool ok = yok0 && (unsigned)xx < (unsigned)W;
          int pi = rb0 + min(max(xx, 0), W - 1);
          bf16x8 bm = a1v[pi * 4 + q];
          bf16x8 bx = qlo ? xv16[pi * 2 + q] : zero;
          if (!ok) { bm = zero; bx = zero; }
          aA0[0] = __builtin_amdgcn_mfma_f32_16x16x32_bf16(am0, bm, aA0[0], 0, 0, 0);
          aA1[0] = __builtin_amdgcn_mfma_f32_16x16x32_bf16(am1, bm, aA1[0], 0, 0, 0);
          aB0[0] = __builtin_amdgcn_mfma_f32_16x16x32_bf16(ad0, bx, aB0[0], 0, 0, 0);
          aB1[0] = __builtin_amdgcn_mfma_f32_16x16x32_bf16(ad1, bx, aB1[0], 0, 0, 0);
        }
        {  // group 1
          int xx = x1g + n - 1 + kx;
          bool ok = yok1 && (unsigned)xx < (unsigned)W;
          int pi = rb1 + min(max(xx, 0), W - 1);
          bf16x8 bm = a1v[pi * 4 + q];
          bf16x8 bx = qlo ? xv16[pi * 2 + q] : zero;
          if (!ok) { bm = zero; bx = zero; }
          aA0[1] = __builtin_amdgcn_mfma_f32_16x16x32_bf16(am0, bm, aA0[1], 0, 0, 0);
          aA1[1] = __builtin_amdgcn_mfma_f32_16x16x32_bf16(am1, bm, aA1[1], 0, 0, 0);
          aB0[1] = __builtin_amdgcn_mfma_f32_16x16x32_bf16(ad0, bx, aB0[1], 0, 0, 0);
          aB1[1] = __builtin_amdgcn_mfma_f32_16x16x32_bf16(ad1, bx, aB1[1], 0, 0, 0);
        }
      }
    }
  }

#pragma unroll
  for (int g = 0; g < 2; g++) {
    const int Pg = P0 + 16 * g;
#pragma unroll
    for (int r = 0; r < 4; r++) {
      int co = q * 4 + r;
      A[co * DHW + Pg + n] = aA0[g][r];
      A[(co + 16) * DHW + Pg + n] = aA1[g][r];
      Bb[co * DHW + Pg + n] = aB0[g][r];
      Bb[(co + 16) * DHW + Pg + n] = aB1[g][r];
    }
  }

  STATS_RED2(aA0[0], aA0[1], 0)
  STATS_RED2(aA1[0], aA1[1], 16)
  STATS_RED2(aB0[0], aB0[1], 32)
  STATS_RED2(aB1[0], aB1[1], 48)
  __syncthreads();
  if (t < 64) {
    float s = 0.f, qq = 0.f;
    for (int w = 0; w < 16; w++) { s += ls[w * 64 + t]; qq += lq[w * 64 + t]; }
    if (t < 32) {
      atomicAdd(&S[2048 + t], s);
      atomicAdd(&S[2080 + t], qq);
    } else {
      atomicAdd(&S[2112 + t - 32], s);
      atomicAdd(&S[2144 + t - 32], qq);
    }
  }
}

// two-pass fallback: stats only (proven)
__global__ __launch_bounds__(1024) void conv_mfma_stats_kernel(const u16* __restrict__ a1ch,
                                                               const u16* __restrict__ xch16,
                                                               const u16* __restrict__ w2f,
                                                               const u16* __restrict__ wdf,
                                                               float* __restrict__ S) {
  __shared__ u16 w2s[27648];
  __shared__ float ls[16 * 64], lq[16 * 64];
  {
    const uint4* src = (const uint4*)w2f;
    uint4* dst = (uint4*)w2s;
    for (int i = threadIdx.x; i < 3456; i += 1024) dst[i] = src[i];
  }
  __syncthreads();

  const int hw = blockIdx.x;
  const int bid = (hw & 7) * 320 + (hw >> 3);
  const int t = threadIdx.x;
  const int l = t & 63, wv = t >> 6;
  const int n = l & 15, q = l >> 4;
  const int P = bid * 256 + wv * 16;
  const int d = P / HW;
  const int rp = P % HW;
  const int y = rp / W, xc0 = rp % W;

  f32x4 A0 = {0.f, 0.f, 0.f, 0.f}, A1 = {0.f, 0.f, 0.f, 0.f};
  f32x4 B0 = {0.f, 0.f, 0.f, 0.f}, B1 = {0.f, 0.f, 0.f, 0.f};
  conv_core_lds((const bf16x8*)a1ch, (const bf16x8*)xch16, (const bf16x8*)w2s,
                (const bf16x8*)wdf, d, y, xc0 + n, q, l, A0, A1, B0, B1);

  STATS_RED(A0, 0)
  STATS_RED(A1, 16)
  STATS_RED(B0, 32)
  STATS_RED(B1, 48)
  __syncthreads();
  if (t < 64) {
    float s = 0.f, qq = 0.f;
    for (int w = 0; w < 16; w++) { s += ls[w * 64 + t]; qq += lq[w * 64 + t]; }
    if (t < 32) {
      atomicAdd(&S[2048 + t], s);
      atomicAdd(&S[2080 + t], qq);
    } else {
      atomicAdd(&S[2112 + t - 32], s);
      atomicAdd(&S[2144 + t - 32], qq);
    }
  }
}

__global__ void bn3_final_kernel(float* __restrict__ S, const float* __restrict__ g2f,
                                 const float* __restrict__ b2f, const float* __restrict__ gdf,
                                 const float* __restrict__ bdf) {
  int t = threadIdx.x;  // 64 threads
  if (t < 32) {
    float mean = S[2048 + t] / (float)DHW;
    float var = S[2080 + t] / (float)DHW - mean * mean;
    float sc = g2f[t] * rsqrtf(var + EPS);
    S[2176 + t] = sc;
    S[2208 + t] = b2f[t] - mean * sc;
  } else {
    int c = t - 32;
    float mean = S[2112 + c] / (float)DHW;
    float var = S[2144 + c] / (float)DHW - mean * mean;
    float sc = gdf[c] * rsqrtf(var + EPS);
    S[2240 + c] = sc;
    S[2272 + c] = bdf[c] - mean * sc;
  }
}

// store path: elementwise combine, fp32 inputs
__global__ __launch_bounds__(256) void combine32_kernel(const float* __restrict__ A,
                                                        const float* __restrict__ Bb,
                                                        const float* __restrict__ S,
                                                        const int* __restrict__ flagp,
                                                        void* __restrict__ out) {
  int i = (blockIdx.x * 256 + threadIdx.x) * 4;
  int co = i / DHW;
  float s2 = S[2176 + co], o2 = S[2208 + co];
  float sd = S[2240 + co], od = S[2272 + co];
  float4 va = *(const float4*)(A + i);
  float4 vb = *(const float4*)(Bb + i);
  float r0 = fmaxf(va.x * s2 + o2 + vb.x * sd + od, 0.f);
  float r1 = fmaxf(va.y * s2 + o2 + vb.y * sd + od, 0.f);
  float r2 = fmaxf(va.z * s2 + o2 + vb.z * sd + od, 0.f);
  float r3 = fmaxf(va.w * s2 + o2 + vb.w * sd + od, 0.f);
  int bf = flagp[0];
  if (bf) {
    ushort4 st;
    st.x = f2bf(r0); st.y = f2bf(r1); st.z = f2bf(r2); st.w = f2bf(r3);
    *(ushort4*)((u16*)out + i) = st;
  } else {
    float4 st;
    st.x = r0; st.y = r1; st.z = r2; st.w = r3;
    *(float4*)((float*)out + i) = st;
  }
}

// two-pass fallback: recompute convs, fuse BN3 + add + relu (proven)
__global__ __launch_bounds__(256) void conv_mfma_final_kernel(const u16* __restrict__ a1ch,
                                                              const u16* __restrict__ xch16,
                                                              const u16* __restrict__ w2f,
                                                              const u16* __restrict__ wdf,
                                                              const float* __restrict__ S,
                                                              const int* __restrict__ flagp,
                                                              void* __restrict__ out) {
  __shared__ u16 w2s[27648];
  {
    const uint4* src = (const uint4*)w2f;
    uint4* dst = (uint4*)w2s;
    for (int i = threadIdx.x; i < 3456; i += 256) dst[i] = src[i];
  }
  __syncthreads();

  const int hw = blockIdx.x;                   // grid = 10240
  const int bid = (hw & 7) * 1280 + (hw >> 3);
  const int t = threadIdx.x;
  const int l = t & 63, wv = t >> 6;
  const int n = l & 15, q = l >> 4;
  const int P = bid * 64 + wv * 16;
  const int d = P / HW;
  const int rp = P % HW;
  const int y = rp / W, xc0 = rp % W;

  f32x4 A0 = {0.f, 0.f, 0.f, 0.f}, A1 = {0.f, 0.f, 0.f, 0.f};
  f32x4 B0 = {0.f, 0.f, 0.f, 0.f}, B1 = {0.f, 0.f, 0.f, 0.f};
  conv_core_lds((const bf16x8*)a1ch, (const bf16x8*)xch16, (const bf16x8*)w2s,
                (const bf16x8*)wdf, d, y, xc0 + n, q, l, A0, A1, B0, B1);

  const int bf = flagp[0];
#pragma unroll
  for (int r = 0; r < 4; r++) {
    int co = q * 4 + r;
    {
      float s2 = S[2176 + co], o2 = S[2208 + co];
      float sd = S[2240 + co], od = S[2272 + co];
      float v = fmaxf(A0[r] * s2 + o2 + B0[r] * sd + od, 0.f);
      int ai = co * DHW + P + n;
      if (bf) ((u16*)out)[ai] = f2bf(v);
      else ((float*)out)[ai] = v;
    }
    {
      int c2 = co + 16;
      float s2 = S[2176 + c2], o2 = S[2208 + c2];
      float sd = S[2240 + c2], od = S[2272 + c2];
      float v = fmaxf(A1[r] * s2 + o2 + B1[r] * sd + od, 0.f);
      int ai = c2 * DHW + P + n;
      if (bf) ((u16*)out)[ai] = f2bf(v);
      else ((float*)out)[ai] = v;
    }
  }
}

extern "C" void kernel_launch(void* const* d_in, const int* in_sizes, int n_in,
                              void* d_out, int out_size, void* d_ws, size_t ws_size,
                              hipStream_t stream) {
  const void* x = d_in[0];
  const void* f = d_in[1];

  char* ws = (char*)d_ws;
  float* S = (float*)ws;
  int* flag = (int*)ws + FLAG_SLOT;
  float* WF = (float*)(ws + WF_OFF);
  u16* a1ch = (u16*)(ws + A1CH_OFF);
  u16* xch16 = (u16*)(ws + XCH16_OFF);

  zero_kernel<<<16, 256, 0, stream>>>(S);
  sniff_kernel<<<1, 256, 0, stream>>>((const u16*)x, flag);

  // inputs: x,f,w_off,w_reg,g1,b1,w2,g2,b2,wd,gd,bd
  cvt_all_kernel<<<191, 256, 0, stream>>>(d_in[2], d_in[3], d_in[6], d_in[9], d_in[4], d_in[5],
                                          d_in[7], d_in[8], d_in[10], d_in[11], WF, flag);

  const int store = (ws_size >= NEED_STORE) ? 1 : 0;
  u16* w2frag = (u16*)(ws + (store ? FRAGS_W2 : FRAG2P_W2));
  u16* wdfrag = (u16*)(ws + (store ? FRAGS_WD : FRAG2P_WD));

  prep_kernel<<<245, 256, 0, stream>>>(WF, WF + WOFFT_O, WF + WREGT_O, w2frag, wdfrag);
  chpose_kernel<<<DHW / 256, 256, 0, stream>>>(x, xch16, flag);

  deform_chm_kernel<<<2560, 256, 0, stream>>>(x, f, WF + WOFFT_O, WF + WREGT_O, a1ch, flag, S);
  bn1_scale_kernel<<<4, 256, 0, stream>>>(S, WF + G1_O, WF + B1_O);
  bn1_apply_ch_kernel<<<DHW / 256, 256, 0, stream>>>(a1ch, S);

  if (store) {
    float* A = (float*)(ws + STA_OFF);
    float* Bb = (float*)(ws + STB_OFF);
    conv_mfma_store_kernel<<<1280, 1024, 0, stream>>>(a1ch, xch16, w2frag, wdfrag, A, Bb, S);
    bn3_final_kernel<<<1, 64, 0, stream>>>(S, WF + G2_O, WF + B2_O, WF + GD_O, WF + BD_O);
    combine32_kernel<<<NOUT / 1024, 256, 0, stream>>>(A, Bb, S, flag, d_out);
  } else {
    conv_mfma_stats_kernel<<<2560, 1024, 0, stream>>>(a1ch, xch16, w2frag, wdfrag, S);
    bn3_final_kernel<<<1, 64, 0, stream>>>(S, WF + G2_O, WF + B2_O, WF + GD_O, WF + BD_O);
    conv_mfma_final_kernel<<<10240, 256, 0, stream>>>(a1ch, xch16, w2frag, wdfrag, S, flag,
                                                      d_out);
  }
}

// Round 13
// 688.555 us; speedup vs baseline: 1.1624x; 1.0299x over previous
//
#include <hip/hip_runtime.h>

using u16 = unsigned short;

constexpr int CIN = 16, COUT = 32, COFF = 16;
constexpr int D = 32, H = 128, W = 160;
constexpr int HW = H * W;         // 20480
constexpr int DHW = D * HW;       // 655360
constexpr int NOUT = COUT * DHW;  // 20971520
constexpr float EPS = 1e-5f;

// ---- workspace layout (byte offsets) ----
constexpr size_t WF_OFF = 16384;
constexpr size_t A1CH_OFF = 262144;        // a1ch [pix][32ch] bf16: 41,943,040
constexpr size_t XCH16_OFF = 42205184;     // xch16 [pix][16ch] bf16: 20,971,520
constexpr size_t FRAG2P_W2 = 84148224;     // frag slots, two-pass path
constexpr size_t FRAG2P_WD = 84203520;
constexpr size_t NEED_2PASS = 84258816;
constexpr size_t STA_OFF = 63176704;       // fp32 A
constexpr size_t STB_OFF = 147062784;      // fp32 B
constexpr size_t FRAGS_W2 = 230948864;     // frag slots, store path (after B)
constexpr size_t FRAGS_WD = 231004160;
constexpr size_t NEED_STORE = 231059456;
// WF float-offsets
constexpr int WOFF_O = 0, WREG_O = 2592, W2_O = 7200, WD_O = 34848;
constexpr int G1_O = 48672, B1_O = 48704, G2_O = 48736, B2_O = 48768, GD_O = 48800, BD_O = 48832;
constexpr int WOFFT_O = 49152, WREGT_O = 52224;  // transposed weights (ends 56832, fits)
constexpr int FLAG_SLOT = 3000;

typedef short bf16x8 __attribute__((ext_vector_type(8)));
typedef float f32x4 __attribute__((ext_vector_type(4)));
typedef u16 u16x8 __attribute__((ext_vector_type(8)));

static __device__ __forceinline__ float bf2f(u16 h) {
  unsigned u = ((unsigned)h) << 16;
  float f;
  __builtin_memcpy(&f, &u, 4);
  return f;
}
static __device__ __forceinline__ u16 f2bf(float f) {
  unsigned u;
  __builtin_memcpy(&u, &f, 4);
  u += 0x7fffu + ((u >> 16) & 1u);
  return (u16)(u >> 16);
}
static __device__ __forceinline__ float ldin(const void* p, int i, int bf) {
  float r;
  if (bf) r = bf2f(((const u16*)p)[i]);
  else r = ((const float*)p)[i];
  return r;
}

__global__ __launch_bounds__(256) void zero_kernel(float* __restrict__ S) {
  S[blockIdx.x * 256 + threadIdx.x] = 0.f;
}

__global__ __launch_bounds__(256) void sniff_kernel(const u16* __restrict__ x,
                                                    int* __restrict__ flag) {
  __shared__ int sh[256];
  int cnt = 0;
  for (int i = threadIdx.x; i < 4096; i += 256) {
    int e = (x[i] >> 7) & 0xff;
    cnt += (e >= 96 && e <= 144) ? 1 : 0;
  }
  sh[threadIdx.x] = cnt;
  __syncthreads();
  for (int s = 128; s > 0; s >>= 1) {
    if (threadIdx.x < (unsigned)s) sh[threadIdx.x] += sh[threadIdx.x + s];
    __syncthreads();
  }
  if (threadIdx.x == 0) flag[0] = (sh[0] > 3072) ? 1 : 0;
}

// all 10 input conversions in one launch
__global__ __launch_bounds__(256) void cvt_all_kernel(
    const void* s0, const void* s1, const void* s2, const void* s3, const void* s4,
    const void* s5, const void* s6, const void* s7, const void* s8, const void* s9,
    float* __restrict__ WF, const int* __restrict__ flagp) {
  const int bf = flagp[0];
  int i = blockIdx.x * 256 + threadIdx.x;
  if (i < 2592) { WF[WOFF_O + i] = ldin(s0, i, bf); return; }
  i -= 2592;
  if (i < 4608) { WF[WREG_O + i] = ldin(s1, i, bf); return; }
  i -= 4608;
  if (i < 27648) { WF[W2_O + i] = ldin(s2, i, bf); return; }
  i -= 27648;
  if (i < 13824) { WF[WD_O + i] = ldin(s3, i, bf); return; }
  i -= 13824;
  if (i < 32) { WF[G1_O + i] = ldin(s4, i, bf); return; }
  i -= 32;
  if (i < 32) { WF[B1_O + i] = ldin(s5, i, bf); return; }
  i -= 32;
  if (i < 32) { WF[G2_O + i] = ldin(s6, i, bf); return; }
  i -= 32;
  if (i < 32) { WF[B2_O + i] = ldin(s7, i, bf); return; }
  i -= 32;
  if (i < 32) { WF[GD_O + i] = ldin(s8, i, bf); return; }
  i -= 32;
  if (i < 32) { WF[BD_O + i] = ldin(s9, i, bf); }
}

// all weight reshapes/packs in one launch (depends on cvt_all output)
__global__ __launch_bounds__(256) void prep_kernel(const float* __restrict__ WF,
                                                   float* __restrict__ wofft,
                                                   float* __restrict__ wregt,
                                                   u16* __restrict__ w2frag,
                                                   u16* __restrict__ wdfrag) {
  int i = blockIdx.x * 256 + threadIdx.x;
  if (i < 2592) {  // w_off [18][144] -> [144][18]
    int ch = i / 144, widx = i % 144;
    wofft[widx * 18 + ch] = WF[WOFF_O + i];
    return;
  }
  i -= 2592;
  if (i < 4608) {  // w_reg [32][144] -> [144][32]
    int co = i / 144, k = i % 144;
    wregt[k * 32 + co] = WF[WREG_O + i];
    return;
  }
  i -= 4608;
  if (i < 27648) {  // pack w2 frags (nci=32)
    int j = i & 7, l = (i >> 3) & 63, cotile = (i >> 9) & 1, tap = i >> 10;
    int co = cotile * 16 + (l & 15);
    int k = (l >> 4) * 8 + j;
    w2frag[i] = f2bf(WF[W2_O + (co * 32 + k) * 27 + tap]);
    return;
  }
  i -= 27648;
  if (i < 27648) {  // pack wd frags (nci=16, zero-pad k>=16)
    int j = i & 7, l = (i >> 3) & 63, cotile = (i >> 9) & 1, tap = i >> 10;
    int co = cotile * 16 + (l & 15);
    int k = (l >> 4) * 8 + j;
    float v = (k < 16) ? WF[WD_O + (co * 16 + k) * 27 + tap] : 0.f;
    wdfrag[i] = f2bf(v);
  }
}

// Deformable conv (proven R9 structure): channel-major coalesced loads +
// XCD swizzle + transposed weights + channels-last bf16 output + BN1 stats.
// v4: also emits this pixel's xch16 row (folds the chpose kernel).
__global__ __launch_bounds__(256) void deform_chm_kernel(const void* __restrict__ x,
                                                         const void* __restrict__ f,
                                                         const float* __restrict__ w_off_t,
                                                         const float* __restrict__ w_reg_t,
                                                         u16* __restrict__ a1ch,
                                                         u16* __restrict__ xch16,
                                                         const int* __restrict__ flagp,
                                                         float* __restrict__ S) {
  const int bf = flagp[0];
  const int hw = blockIdx.x;                 // grid = 2560, %8 == 0
  const int bid = (hw & 7) * 320 + (hw >> 3);
  const int d = bid / 80;
  const int p = (bid % 80) * 256 + threadIdx.x;
  const int y = p / W;
  const int xx = p % W;
  const int dbase = d * HW;

  // fold chpose: write this pixel's 16 x-channels to xch16 (coalesced loads)
  {
    u16 sv[16];
#pragma unroll
    for (int ci = 0; ci < 16; ci++) sv[ci] = f2bf(ldin(x, ci * DHW + dbase + p, bf));
    uint4 u0, u1;
    u0.x = (unsigned)sv[0] | ((unsigned)sv[1] << 16);
    u0.y = (unsigned)sv[2] | ((unsigned)sv[3] << 16);
    u0.z = (unsigned)sv[4] | ((unsigned)sv[5] << 16);
    u0.w = (unsigned)sv[6] | ((unsigned)sv[7] << 16);
    u1.x = (unsigned)sv[8] | ((unsigned)sv[9] << 16);
    u1.y = (unsigned)sv[10] | ((unsigned)sv[11] << 16);
    u1.z = (unsigned)sv[12] | ((unsigned)sv[13] << 16);
    u1.w = (unsigned)sv[14] | ((unsigned)sv[15] << 16);
    const size_t xb = (size_t)(dbase + p) * 16;
    *(uint4*)(xch16 + xb) = u0;
    *(uint4*)(xch16 + xb + 8) = u1;
  }

  float doff[18];
#pragma unroll
  for (int t = 0; t < 18; t++) doff[t] = 0.f;
  for (int ci = 0; ci < COFF; ci++) {
    const int fbase = ci * DHW + dbase;
#pragma unroll
    for (int ki = 0; ki < 3; ki++) {
      int yy = y - 1 + ki;
      bool yok = (unsigned)yy < (unsigned)H;
#pragma unroll
      for (int kj = 0; kj < 3; kj++) {
        int xj = xx - 1 + kj;
        float v = (yok && (unsigned)xj < (unsigned)W) ? ldin(f, fbase + yy * W + xj, bf) : 0.f;
        int widx = ci * 9 + ki * 3 + kj;
#pragma unroll
        for (int t = 0; t < 18; t++) doff[t] += v * w_off_t[widx * 18 + t];
      }
    }
  }

  float acc[COUT];
#pragma unroll
  for (int co = 0; co < COUT; co++) acc[co] = 0.f;

#pragma unroll
  for (int t = 0; t < 9; t++) {
    float dy = fminf(fmaxf(doff[2 * t], -1.f), 1.f);
    float dx = fminf(fmaxf(doff[2 * t + 1], -1.f), 1.f);
    float py = (float)(y - 1 + t / 3) + dy;
    float px = (float)(xx - 1 + t % 3) + dx;
    float y0f = floorf(py), x0f = floorf(px);
    float wy1 = py - y0f, wx1 = px - x0f;
    int y0 = (int)y0f, x0i = (int)x0f;
    int y1 = y0 + 1, x1 = x0i + 1;
    bool y0v = (unsigned)y0 < (unsigned)H, y1v = (unsigned)y1 < (unsigned)H;
    bool x0v = (unsigned)x0i < (unsigned)W, x1v = (unsigned)x1 < (unsigned)W;
    float c00 = (y0v && x0v) ? (1.f - wy1) * (1.f - wx1) : 0.f;
    float c01 = (y0v && x1v) ? (1.f - wy1) * wx1 : 0.f;
    float c10 = (y1v && x0v) ? wy1 * (1.f - wx1) : 0.f;
    float c11 = (y1v && x1v) ? wy1 * wx1 : 0.f;
    int y0c = min(max(y0, 0), H - 1) * W, y1c = min(max(y1, 0), H - 1) * W;
    int x0c = min(max(x0i, 0), W - 1), x1c = min(max(x1, 0), W - 1);

    for (int ci = 0; ci < CIN; ci++) {
      const int xbase = ci * DHW + dbase;
      float s = c00 * ldin(x, xbase + y0c + x0c, bf) + c01 * ldin(x, xbase + y0c + x1c, bf) +
                c10 * ldin(x, xbase + y1c + x0c, bf) + c11 * ldin(x, xbase + y1c + x1c, bf);
      const float* wp = w_reg_t + (ci * 9 + t) * 32;
#pragma unroll
      for (int co = 0; co < COUT; co++) acc[co] += s * wp[co];
    }
  }

  // store channels-last bf16
  u16 hh[COUT];
#pragma unroll
  for (int co = 0; co < COUT; co++) hh[co] = f2bf(acc[co]);
  const size_t pb = ((size_t)dbase + p) * 32;
#pragma unroll
  for (int k = 0; k < 4; k++) {
    uint4 u;
    u.x = (unsigned)hh[8 * k + 0] | ((unsigned)hh[8 * k + 1] << 16);
    u.y = (unsigned)hh[8 * k + 2] | ((unsigned)hh[8 * k + 3] << 16);
    u.z = (unsigned)hh[8 * k + 4] | ((unsigned)hh[8 * k + 5] << 16);
    u.w = (unsigned)hh[8 * k + 6] | ((unsigned)hh[8 * k + 7] << 16);
    *(uint4*)(a1ch + pb + 8 * k) = u;
  }

  // fused BN1 stats on bf16-rounded values
  const int l = threadIdx.x & 63;
  const int wv = threadIdx.x >> 6;
  __shared__ float ls[128], lq[128];
#pragma unroll
  for (int co = 0; co < COUT; co++) {
    float v = bf2f(hh[co]);
    float s = v, qq = v * v;
    s += __shfl_xor(s, 1);  qq += __shfl_xor(qq, 1);
    s += __shfl_xor(s, 2);  qq += __shfl_xor(qq, 2);
    s += __shfl_xor(s, 4);  qq += __shfl_xor(qq, 4);
    s += __shfl_xor(s, 8);  qq += __shfl_xor(qq, 8);
    s += __shfl_xor(s, 16); qq += __shfl_xor(qq, 16);
    s += __shfl_xor(s, 32); qq += __shfl_xor(qq, 32);
    if (l == 0) { ls[wv * 32 + co] = s; lq[wv * 32 + co] = qq; }
  }
  __syncthreads();
  if (threadIdx.x < 32) {
    int c = threadIdx.x;
    float s = ls[c] + ls[32 + c] + ls[64 + c] + ls[96 + c];
    float qq = lq[c] + lq[32 + c] + lq[64 + c] + lq[96 + c];
    atomicAdd(&S[c * D + d], s);
    atomicAdd(&S[1024 + c * D + d], qq);
  }
}

// BN1 apply; scale/offset computed in-block from raw sums (folds bn1_scale),
// bit-identical formula.
__global__ __launch_bounds__(256) void bn1_apply_ch_kernel(u16* __restrict__ a1ch,
                                                           const float* __restrict__ S,
                                                           const float* __restrict__ g1f,
                                                           const float* __restrict__ b1f) {
  __shared__ float sc[32], of[32];
  const int b = blockIdx.x;
  const int d = b / (HW / 256);
  if (threadIdx.x < 32) {
    int c = threadIdx.x;
    float mean = S[c * D + d] / (float)HW;
    float var = S[1024 + c * D + d] / (float)HW - mean * mean;
    float scv = g1f[c] * rsqrtf(var + EPS);
    sc[c] = scv;
    of[c] = b1f[c] - mean * scv;
  }
  __syncthreads();
  const size_t pb = ((size_t)b * 256 + threadIdx.x) * 32;
#pragma unroll
  for (int k = 0; k < 4; k++) {
    uint4 u = *(const uint4*)(a1ch + pb + 8 * k);
    unsigned w[4] = {u.x, u.y, u.z, u.w};
    unsigned ov[4];
#pragma unroll
    for (int m = 0; m < 4; m++) {
      int c0 = k * 8 + m * 2;
      float lo = bf2f((u16)(w[m] & 0xffffu));
      float hi = bf2f((u16)(w[m] >> 16));
      lo = fmaxf(lo * sc[c0] + of[c0], 0.f);
      hi = fmaxf(hi * sc[c0 + 1] + of[c0 + 1], 0.f);
      ov[m] = (unsigned)f2bf(lo) | ((unsigned)f2bf(hi) << 16);
    }
    uint4 o;
    o.x = ov[0]; o.y = ov[1]; o.z = ov[2]; o.w = ov[3];
    *(uint4*)(a1ch + pb + 8 * k) = o;
  }
}

// legacy core for the two-pass fallback path (unchanged, proven)
static __device__ __forceinline__ void conv_core_lds(const bf16x8* __restrict__ a1v,
                                                     const bf16x8* __restrict__ xv16,
                                                     const bf16x8* __restrict__ w2s,  // LDS
                                                     const bf16x8* __restrict__ wdv,
                                                     int d, int y, int xn, int q, int l,
                                                     f32x4& A0, f32x4& A1, f32x4& B0, f32x4& B1) {
  const bf16x8 zero = {0, 0, 0, 0, 0, 0, 0, 0};
  const bool qlo = (q < 2);
#pragma unroll
  for (int kd = 0; kd < 3; kd++) {
    int dd = d - 1 + kd;
    if ((unsigned)dd >= (unsigned)D) continue;
#pragma unroll
    for (int ky = 0; ky < 3; ky++) {
      int yy = y - 1 + ky;
      if ((unsigned)yy >= (unsigned)H) continue;
      const int rowb = dd * HW + yy * W;
#pragma unroll
      for (int kx = 0; kx < 3; kx++) {
        int xx = xn - 1 + kx;
        bool ok = (unsigned)xx < (unsigned)W;
        int xc = min(max(xx, 0), W - 1);
        int pi = rowb + xc;
        bf16x8 bm = a1v[pi * 4 + q];
        bf16x8 bx = qlo ? xv16[pi * 2 + q] : zero;
        if (!ok) { bm = zero; bx = zero; }
        const int tb = (kd * 9 + ky * 3 + kx) * 2;
        bf16x8 am0 = w2s[(tb + 0) * 64 + l];
        bf16x8 am1 = w2s[(tb + 1) * 64 + l];
        bf16x8 ad0 = qlo ? wdv[(tb + 0) * 64 + l] : zero;
        bf16x8 ad1 = qlo ? wdv[(tb + 1) * 64 + l] : zero;
        A0 = __builtin_amdgcn_mfma_f32_16x16x32_bf16(am0, bm, A0, 0, 0, 0);
        A1 = __builtin_amdgcn_mfma_f32_16x16x32_bf16(am1, bm, A1, 0, 0, 0);
        B0 = __builtin_amdgcn_mfma_f32_16x16x32_bf16(ad0, bx, B0, 0, 0, 0);
        B1 = __builtin_amdgcn_mfma_f32_16x16x32_bf16(ad1, bx, B1, 0, 0, 0);
      }
    }
  }
}

#define STATS_RED(ACC, BASE)                                                          \
  {                                                                                   \
    _Pragma("unroll") for (int r = 0; r < 4; r++) {                                   \
      float v = ACC[r];                                                               \
      float s = v, qq = v * v;                                                        \
      s += __shfl_xor(s, 1); qq += __shfl_xor(qq, 1);                                 \
      s += __shfl_xor(s, 2); qq += __shfl_xor(qq, 2);                                 \
      s += __shfl_xor(s, 4); qq += __shfl_xor(qq, 4);                                 \
      s += __shfl_xor(s, 8); qq += __shfl_xor(qq, 8);                                 \
      if (n == 0) {                                                                   \
        int ci = (BASE) + q * 4 + r;                                                  \
        ls[wv * 64 + ci] = s;                                                         \
        lq[wv * 64 + ci] = qq;                                                        \
      }                                                                               \
    }                                                                                 \
  }

#define STATS_RED2(Aa, Ab, BASE)                                                      \
  {                                                                                   \
    _Pragma("unroll") for (int r = 0; r < 4; r++) {                                   \
      float v0 = Aa[r], v1 = Ab[r];                                                   \
      float s = v0 + v1, qq = v0 * v0 + v1 * v1;                                      \
      s += __shfl_xor(s, 1); qq += __shfl_xor(qq, 1);                                 \
      s += __shfl_xor(s, 2); qq += __shfl_xor(qq, 2);                                 \
      s += __shfl_xor(s, 4); qq += __shfl_xor(qq, 4);                                 \
      s += __shfl_xor(s, 8); qq += __shfl_xor(qq, 8);                                 \
      if (n == 0) {                                                                   \
        int ci = (BASE) + q * 4 + r;                                                  \
        ls[wv * 64 + ci] = s;                                                         \
        lq[wv * 64 + ci] = qq;                                                        \
      }                                                                               \
    }                                                                                 \
  }

// store-once v3 (proven R9): 32 pixels (2 groups) per wave.
__global__ __launch_bounds__(1024) void conv_mfma_store_kernel(const u16* __restrict__ a1ch,
                                                               const u16* __restrict__ xch16,
                                                               const u16* __restrict__ w2f,
                                                               const u16* __restrict__ wdf,
                                                               float* __restrict__ A,
                                                               float* __restrict__ Bb,
                                                               float* __restrict__ S) {
  __shared__ u16 w2s[27648];  // 55296 B
  __shared__ float ls[16 * 64], lq[16 * 64];
  {
    const uint4* src = (const uint4*)w2f;
    uint4* dst = (uint4*)w2s;
    for (int i = threadIdx.x; i < 3456; i += 1024) dst[i] = src[i];
  }
  __syncthreads();

  const int hw = blockIdx.x;                 // grid = 1280, %8 == 0
  const int bid = (hw & 7) * 160 + (hw >> 3);
  const int t = threadIdx.x;
  const int l = t & 63, wv = t >> 6;
  const int n = l & 15, q = l >> 4;
  const int P0 = bid * 512 + wv * 32;        // 2 groups: P0, P0+16 (same d)
  const int d = P0 / HW;
  const int rp0 = P0 % HW;
  const int y0 = rp0 / W, x0 = rp0 % W;
  const int rp1 = (P0 + 16) % HW;
  const int y1g = rp1 / W, x1g = rp1 % W;

  const bf16x8 zero = {0, 0, 0, 0, 0, 0, 0, 0};
  const bool qlo = (q < 2);
  const bf16x8* a1v = (const bf16x8*)a1ch;
  const bf16x8* xv16 = (const bf16x8*)xch16;
  const bf16x8* w2v = (const bf16x8*)w2s;
  const bf16x8* wdv = (const bf16x8*)wdf;

  f32x4 aA0[2], aA1[2], aB0[2], aB1[2];
#pragma unroll
  for (int g = 0; g < 2; g++) {
    aA0[g] = (f32x4){0.f, 0.f, 0.f, 0.f};
    aA1[g] = (f32x4){0.f, 0.f, 0.f, 0.f};
    aB0[g] = (f32x4){0.f, 0.f, 0.f, 0.f};
    aB1[g] = (f32x4){0.f, 0.f, 0.f, 0.f};
  }

#pragma unroll
  for (int kd = 0; kd < 3; kd++) {
    int dd = d - 1 + kd;
    if ((unsigned)dd >= (unsigned)D) continue;
#pragma unroll
    for (int ky = 0; ky < 3; ky++) {
      int yy0 = y0 - 1 + ky, yy1 = y1g - 1 + ky;
      bool yok0 = (unsigned)yy0 < (unsigned)H, yok1 = (unsigned)yy1 < (unsigned)H;
      int rb0 = dd * HW + min(max(yy0, 0), H - 1) * W;
      int rb1 = dd * HW + min(max(yy1, 0), H - 1) * W;
#pragma unroll
      for (int kx = 0; kx < 3; kx++) {
        const int tb = (kd * 9 + ky * 3 + kx) * 2;
        bf16x8 am0 = w2v[(tb + 0) * 64 + l];
        bf16x8 am1 = w2v[(tb + 1) * 64 + l];
        bf16x8 ad0 = qlo ? wdv[(tb + 0) * 64 + l] : zero;
        bf16x8 ad1 = qlo ? wdv[(tb + 1) * 64 + l] : zero;
        {  // group 0
          int xx = x0 + n - 1 + kx;
          bool ok = yok0 && (unsigned)xx < (unsigned)W;
          int pi = rb0 + min(max(xx, 0), W - 1);
          bf16x8 bm = a1v[pi * 4 + q];
          bf16x8 bx = qlo ? xv16[pi * 2 + q] : zero;
          if (!ok) { bm = zero; bx = zero; }
          aA0[0] = __builtin_amdgcn_mfma_f32_16x16x32_bf16(am0, bm, aA0[0], 0, 0, 0);
          aA1[0] = __builtin_amdgcn_mfma_f32_16x16x32_bf16(am1, bm, aA1[0], 0, 0, 0);
          aB0[0] = __builtin_amdgcn_mfma_f32_16x16x32_bf16(ad0, bx, aB0[0], 0, 0, 0);
          aB1[0] = __builtin_amdgcn_mfma_f32_16x16x32_bf16(ad1, bx, aB1[0], 0, 0, 0);
        }
        {  // group 1
          int xx = x1g + n - 1 + kx;
          bool ok = yok1 && (unsigned)xx < (unsigned)W;
          int pi = rb1 + min(max(xx, 0), W - 1);
          bf16x8 bm = a1v[pi * 4 + q];
          bf16x8 bx = qlo ? xv16[pi * 2 + q] : zero;
          if (!ok) { bm = zero; bx = zero; }
          aA0[1] = __builtin_amdgcn_mfma_f32_16x16x32_bf16(am0, bm, aA0[1], 0, 0, 0);
          aA1[1] = __builtin_amdgcn_mfma_f32_16x16x32_bf16(am1, bm, aA1[1], 0, 0, 0);
          aB0[1] = __builtin_amdgcn_mfma_f32_16x16x32_bf16(ad0, bx, aB0[1], 0, 0, 0);
          aB1[1] = __builtin_amdgcn_mfma_f32_16x16x32_bf16(ad1, bx, aB1[1], 0, 0, 0);
        }
      }
    }
  }

#pragma unroll
  for (int g = 0; g < 2; g++) {
    const int Pg = P0 + 16 * g;
#pragma unroll
    for (int r = 0; r < 4; r++) {
      int co = q * 4 + r;
      A[co * DHW + Pg + n] = aA0[g][r];
      A[(co + 16) * DHW + Pg + n] = aA1[g][r];
      Bb[co * DHW + Pg + n] = aB0[g][r];
      Bb[(co + 16) * DHW + Pg + n] = aB1[g][r];
    }
  }

  STATS_RED2(aA0[0], aA0[1], 0)
  STATS_RED2(aA1[0], aA1[1], 16)
  STATS_RED2(aB0[0], aB0[1], 32)
  STATS_RED2(aB1[0], aB1[1], 48)
  __syncthreads();
  if (t < 64) {
    float s = 0.f, qq = 0.f;
    for (int w = 0; w < 16; w++) { s += ls[w * 64 + t]; qq += lq[w * 64 + t]; }
    if (t < 32) {
      atomicAdd(&S[2048 + t], s);
      atomicAdd(&S[2080 + t], qq);
    } else {
      atomicAdd(&S[2112 + t - 32], s);
      atomicAdd(&S[2144 + t - 32], qq);
    }
  }
}

// two-pass fallback: stats only (proven)
__global__ __launch_bounds__(1024) void conv_mfma_stats_kernel(const u16* __restrict__ a1ch,
                                                               const u16* __restrict__ xch16,
                                                               const u16* __restrict__ w2f,
                                                               const u16* __restrict__ wdf,
                                                               float* __restrict__ S) {
  __shared__ u16 w2s[27648];
  __shared__ float ls[16 * 64], lq[16 * 64];
  {
    const uint4* src = (const uint4*)w2f;
    uint4* dst = (uint4*)w2s;
    for (int i = threadIdx.x; i < 3456; i += 1024) dst[i] = src[i];
  }
  __syncthreads();

  const int hw = blockIdx.x;
  const int bid = (hw & 7) * 320 + (hw >> 3);
  const int t = threadIdx.x;
  const int l = t & 63, wv = t >> 6;
  const int n = l & 15, q = l >> 4;
  const int P = bid * 256 + wv * 16;
  const int d = P / HW;
  const int rp = P % HW;
  const int y = rp / W, xc0 = rp % W;

  f32x4 A0 = {0.f, 0.f, 0.f, 0.f}, A1 = {0.f, 0.f, 0.f, 0.f};
  f32x4 B0 = {0.f, 0.f, 0.f, 0.f}, B1 = {0.f, 0.f, 0.f, 0.f};
  conv_core_lds((const bf16x8*)a1ch, (const bf16x8*)xch16, (const bf16x8*)w2s,
                (const bf16x8*)wdf, d, y, xc0 + n, q, l, A0, A1, B0, B1);

  STATS_RED(A0, 0)
  STATS_RED(A1, 16)
  STATS_RED(B0, 32)
  STATS_RED(B1, 48)
  __syncthreads();
  if (t < 64) {
    float s = 0.f, qq = 0.f;
    for (int w = 0; w < 16; w++) { s += ls[w * 64 + t]; qq += lq[w * 64 + t]; }
    if (t < 32) {
      atomicAdd(&S[2048 + t], s);
      atomicAdd(&S[2080 + t], qq);
    } else {
      atomicAdd(&S[2112 + t - 32], s);
      atomicAdd(&S[2144 + t - 32], qq);
    }
  }
}

__global__ void bn3_final_kernel(float* __restrict__ S, const float* __restrict__ g2f,
                                 const float* __restrict__ b2f, const float* __restrict__ gdf,
                                 const float* __restrict__ bdf) {
  int t = threadIdx.x;  // 64 threads
  if (t < 32) {
    float mean = S[2048 + t] / (float)DHW;
    float var = S[2080 + t] / (float)DHW - mean * mean;
    float sc = g2f[t] * rsqrtf(var + EPS);
    S[2176 + t] = sc;
    S[2208 + t] = b2f[t] - mean * sc;
  } else {
    int c = t - 32;
    float mean = S[2112 + c] / (float)DHW;
    float var = S[2144 + c] / (float)DHW - mean * mean;
    float sc = gdf[c] * rsqrtf(var + EPS);
    S[2240 + c] = sc;
    S[2272 + c] = bdf[c] - mean * sc;
  }
}

// store path: elementwise combine, fp32 inputs
__global__ __launch_bounds__(256) void combine32_kernel(const float* __restrict__ A,
                                                        const float* __restrict__ Bb,
                                                        const float* __restrict__ S,
                                                        const int* __restrict__ flagp,
                                                        void* __restrict__ out) {
  int i = (blockIdx.x * 256 + threadIdx.x) * 4;
  int co = i / DHW;
  float s2 = S[2176 + co], o2 = S[2208 + co];
  float sd = S[2240 + co], od = S[2272 + co];
  float4 va = *(const float4*)(A + i);
  float4 vb = *(const float4*)(Bb + i);
  float r0 = fmaxf(va.x * s2 + o2 + vb.x * sd + od, 0.f);
  float r1 = fmaxf(va.y * s2 + o2 + vb.y * sd + od, 0.f);
  float r2 = fmaxf(va.z * s2 + o2 + vb.z * sd + od, 0.f);
  float r3 = fmaxf(va.w * s2 + o2 + vb.w * sd + od, 0.f);
  int bf = flagp[0];
  if (bf) {
    ushort4 st;
    st.x = f2bf(r0); st.y = f2bf(r1); st.z = f2bf(r2); st.w = f2bf(r3);
    *(ushort4*)((u16*)out + i) = st;
  } else {
    float4 st;
    st.x = r0; st.y = r1; st.z = r2; st.w = r3;
    *(float4*)((float*)out + i) = st;
  }
}

// two-pass fallback: recompute convs, fuse BN3 + add + relu (proven)
__global__ __launch_bounds__(256) void conv_mfma_final_kernel(const u16* __restrict__ a1ch,
                                                              const u16* __restrict__ xch16,
                                                              const u16* __restrict__ w2f,
                                                              const u16* __restrict__ wdf,
                                                              const float* __restrict__ S,
                                                              const int* __restrict__ flagp,
                                                              void* __restrict__ out) {
  __shared__ u16 w2s[27648];
  {
    const uint4* src = (const uint4*)w2f;
    uint4* dst = (uint4*)w2s;
    for (int i = threadIdx.x; i < 3456; i += 256) dst[i] = src[i];
  }
  __syncthreads();

  const int hw = blockIdx.x;                   // grid = 10240
  const int bid = (hw & 7) * 1280 + (hw >> 3);
  const int t = threadIdx.x;
  const int l = t & 63, wv = t >> 6;
  const int n = l & 15, q = l >> 4;
  const int P = bid * 64 + wv * 16;
  const int d = P / HW;
  const int rp = P % HW;
  const int y = rp / W, xc0 = rp % W;

  f32x4 A0 = {0.f, 0.f, 0.f, 0.f}, A1 = {0.f, 0.f, 0.f, 0.f};
  f32x4 B0 = {0.f, 0.f, 0.f, 0.f}, B1 = {0.f, 0.f, 0.f, 0.f};
  conv_core_lds((const bf16x8*)a1ch, (const bf16x8*)xch16, (const bf16x8*)w2s,
                (const bf16x8*)wdf, d, y, xc0 + n, q, l, A0, A1, B0, B1);

  const int bf = flagp[0];
#pragma unroll
  for (int r = 0; r < 4; r++) {
    int co = q * 4 + r;
    {
      float s2 = S[2176 + co], o2 = S[2208 + co];
      float sd = S[2240 + co], od = S[2272 + co];
      float v = fmaxf(A0[r] * s2 + o2 + B0[r] * sd + od, 0.f);
      int ai = co * DHW + P + n;
      if (bf) ((u16*)out)[ai] = f2bf(v);
      else ((float*)out)[ai] = v;
    }
    {
      int c2 = co + 16;
      float s2 = S[2176 + c2], o2 = S[2208 + c2];
      float sd = S[2240 + c2], od = S[2272 + c2];
      float v = fmaxf(A1[r] * s2 + o2 + B1[r] * sd + od, 0.f);
      int ai = c2 * DHW + P + n;
      if (bf) ((u16*)out)[ai] = f2bf(v);
      else ((float*)out)[ai] = v;
    }
  }
}

extern "C" void kernel_launch(void* const* d_in, const int* in_sizes, int n_in,
                              void* d_out, int out_size, void* d_ws, size_t ws_size,
                              hipStream_t stream) {
  const void* x = d_in[0];
  const void* f = d_in[1];

  char* ws = (char*)d_ws;
  float* S = (float*)ws;
  int* flag = (int*)ws + FLAG_SLOT;
  float* WF = (float*)(ws + WF_OFF);
  u16* a1ch = (u16*)(ws + A1CH_OFF);
  u16* xch16 = (u16*)(ws + XCH16_OFF);

  zero_kernel<<<16, 256, 0, stream>>>(S);
  sniff_kernel<<<1, 256, 0, stream>>>((const u16*)x, flag);

  // inputs: x,f,w_off,w_reg,g1,b1,w2,g2,b2,wd,gd,bd
  cvt_all_kernel<<<191, 256, 0, stream>>>(d_in[2], d_in[3], d_in[6], d_in[9], d_in[4], d_in[5],
                                          d_in[7], d_in[8], d_in[10], d_in[11], WF, flag);

  const int store = (ws_size >= NEED_STORE) ? 1 : 0;
  u16* w2frag = (u16*)(ws + (store ? FRAGS_W2 : FRAG2P_W2));
  u16* wdfrag = (u16*)(ws + (store ? FRAGS_WD : FRAG2P_WD));

  prep_kernel<<<245, 256, 0, stream>>>(WF, WF + WOFFT_O, WF + WREGT_O, w2frag, wdfrag);

  deform_chm_kernel<<<2560, 256, 0, stream>>>(x, f, WF + WOFFT_O, WF + WREGT_O, a1ch, xch16,
                                              flag, S);
  bn1_apply_ch_kernel<<<DHW / 256, 256, 0, stream>>>(a1ch, S, WF + G1_O, WF + B1_O);

  if (store) {
    float* A = (float*)(ws + STA_OFF);
    float* Bb = (float*)(ws + STB_OFF);
    conv_mfma_store_kernel<<<1280, 1024, 0, stream>>>(a1ch, xch16, w2frag, wdfrag, A, Bb, S);
    bn3_final_kernel<<<1, 64, 0, stream>>>(S, WF + G2_O, WF + B2_O, WF + GD_O, WF + BD_O);
    combine32_kernel<<<NOUT / 1024, 256, 0, stream>>>(A, Bb, S, flag, d_out);
  } else {
    conv_mfma_stats_kernel<<<2560, 1024, 0, stream>>>(a1ch, xch16, w2frag, wdfrag, S);
    bn3_final_kernel<<<1, 64, 0, stream>>>(S, WF + G2_O, WF + B2_O, WF + GD_O, WF + BD_O);
    conv_mfma_final_kernel<<<10240, 256, 0, stream>>>(a1ch, xch16, w2frag, wdfrag, S, flag,
                                                      d_out);
  }
}

// Round 14
// 687.374 us; speedup vs baseline: 1.1644x; 1.0017x over previous
//
#include <hip/hip_runtime.h>

using u16 = unsigned short;

constexpr int CIN = 16, COUT = 32, COFF = 16;
constexpr int D = 32, H = 128, W = 160;
constexpr int HW = H * W;         // 20480
constexpr int DHW = D * HW;       // 655360
constexpr int NOUT = COUT * DHW;  // 20971520
constexpr float EPS = 1e-5f;

// ---- workspace layout (byte offsets) ----
constexpr size_t WF_OFF = 16384;
constexpr size_t A1CH_OFF = 262144;        // a1ch [pix][32ch] bf16: 41,943,040
constexpr size_t XCH16_OFF = 42205184;     // xch16 [pix][16ch] bf16: 20,971,520
constexpr size_t FRAG2P_W2 = 84148224;     // frag slots, two-pass path
constexpr size_t FRAG2P_WD = 84203520;
constexpr size_t NEED_2PASS = 84258816;
constexpr size_t STA_OFF = 63176704;       // fp32 A
constexpr size_t STB_OFF = 147062784;      // fp32 B
constexpr size_t FRAGS_W2 = 230948864;     // frag slots, store path (after B)
constexpr size_t FRAGS_WD = 231004160;
constexpr size_t NEED_STORE = 231059456;
// WF float-offsets (only scalars + transposed weights are materialized now)
constexpr int G1_O = 48672, B1_O = 48704, G2_O = 48736, B2_O = 48768, GD_O = 48800, BD_O = 48832;
constexpr int WOFFT_O = 49152, WREGT_O = 52224;  // transposed weights (ends 56832, fits)
constexpr int FLAG_SLOT = 3000;

typedef short bf16x8 __attribute__((ext_vector_type(8)));
typedef float f32x4 __attribute__((ext_vector_type(4)));
typedef u16 u16x8 __attribute__((ext_vector_type(8)));

static __device__ __forceinline__ float bf2f(u16 h) {
  unsigned u = ((unsigned)h) << 16;
  float f;
  __builtin_memcpy(&f, &u, 4);
  return f;
}
static __device__ __forceinline__ u16 f2bf(float f) {
  unsigned u;
  __builtin_memcpy(&u, &f, 4);
  u += 0x7fffu + ((u >> 16) & 1u);
  return (u16)(u >> 16);
}
static __device__ __forceinline__ float ldin(const void* p, int i, int bf) {
  float r;
  if (bf) r = bf2f(((const u16*)p)[i]);
  else r = ((const float*)p)[i];
  return r;
}

// blocks 0..15: zero S; block 16: sniff dtype flag
__global__ __launch_bounds__(256) void init_kernel(float* __restrict__ S,
                                                   const u16* __restrict__ x,
                                                   int* __restrict__ flag) {
  if (blockIdx.x < 16) {
    S[blockIdx.x * 256 + threadIdx.x] = 0.f;
    return;
  }
  __shared__ int sh[256];
  int cnt = 0;
  for (int i = threadIdx.x; i < 4096; i += 256) {
    int e = (x[i] >> 7) & 0xff;
    cnt += (e >= 96 && e <= 144) ? 1 : 0;
  }
  sh[threadIdx.x] = cnt;
  __syncthreads();
  for (int s = 128; s > 0; s >>= 1) {
    if (threadIdx.x < (unsigned)s) sh[threadIdx.x] += sh[threadIdx.x + s];
    __syncthreads();
  }
  if (threadIdx.x == 0) flag[0] = (sh[0] > 3072) ? 1 : 0;
}

// all weight conversion + reshapes + packs in ONE launch, reading raw inputs.
__global__ __launch_bounds__(256) void prep_kernel(const void* __restrict__ woff_r,
                                                   const void* __restrict__ wreg_r,
                                                   const void* __restrict__ w2_r,
                                                   const void* __restrict__ wd_r,
                                                   const void* __restrict__ g1_r,
                                                   const void* __restrict__ b1_r,
                                                   const void* __restrict__ g2_r,
                                                   const void* __restrict__ b2_r,
                                                   const void* __restrict__ gd_r,
                                                   const void* __restrict__ bd_r,
                                                   float* __restrict__ WF,
                                                   u16* __restrict__ w2frag,
                                                   u16* __restrict__ wdfrag,
                                                   const int* __restrict__ flagp) {
  const int bf = flagp[0];
  int i = blockIdx.x * 256 + threadIdx.x;
  if (i < 2592) {  // w_off raw [18][144] -> wofft [144][18]
    int ch = i / 144, widx = i % 144;
    WF[WOFFT_O + widx * 18 + ch] = ldin(woff_r, i, bf);
    return;
  }
  i -= 2592;
  if (i < 4608) {  // w_reg raw [32][144] -> wregt [144][32]
    int co = i / 144, k = i % 144;
    WF[WREGT_O + k * 32 + co] = ldin(wreg_r, i, bf);
    return;
  }
  i -= 4608;
  if (i < 27648) {  // pack w2 frags (nci=32)
    int j = i & 7, l = (i >> 3) & 63, cotile = (i >> 9) & 1, tap = i >> 10;
    int co = cotile * 16 + (l & 15);
    int k = (l >> 4) * 8 + j;
    w2frag[i] = f2bf(ldin(w2_r, (co * 32 + k) * 27 + tap, bf));
    return;
  }
  i -= 27648;
  if (i < 27648) {  // pack wd frags (nci=16, zero-pad k>=16)
    int j = i & 7, l = (i >> 3) & 63, cotile = (i >> 9) & 1, tap = i >> 10;
    int co = cotile * 16 + (l & 15);
    int k = (l >> 4) * 8 + j;
    float v = (k < 16) ? ldin(wd_r, (co * 16 + k) * 27 + tap, bf) : 0.f;
    wdfrag[i] = f2bf(v);
    return;
  }
  i -= 27648;
  if (i < 32) { WF[G1_O + i] = ldin(g1_r, i, bf); return; }
  i -= 32;
  if (i < 32) { WF[B1_O + i] = ldin(b1_r, i, bf); return; }
  i -= 32;
  if (i < 32) { WF[G2_O + i] = ldin(g2_r, i, bf); return; }
  i -= 32;
  if (i < 32) { WF[B2_O + i] = ldin(b2_r, i, bf); return; }
  i -= 32;
  if (i < 32) { WF[GD_O + i] = ldin(gd_r, i, bf); return; }
  i -= 32;
  if (i < 32) { WF[BD_O + i] = ldin(bd_r, i, bf); }
}

// Deformable conv (proven): channel-major coalesced loads + XCD swizzle +
// transposed weights + channels-last bf16 output + xch16 emission + BN1 stats.
__global__ __launch_bounds__(256) void deform_chm_kernel(const void* __restrict__ x,
                                                         const void* __restrict__ f,
                                                         const float* __restrict__ w_off_t,
                                                         const float* __restrict__ w_reg_t,
                                                         u16* __restrict__ a1ch,
                                                         u16* __restrict__ xch16,
                                                         const int* __restrict__ flagp,
                                                         float* __restrict__ S) {
  const int bf = flagp[0];
  const int hw = blockIdx.x;                 // grid = 2560, %8 == 0
  const int bid = (hw & 7) * 320 + (hw >> 3);
  const int d = bid / 80;
  const int p = (bid % 80) * 256 + threadIdx.x;
  const int y = p / W;
  const int xx = p % W;
  const int dbase = d * HW;

  // fold chpose: write this pixel's 16 x-channels to xch16 (coalesced loads)
  {
    u16 sv[16];
#pragma unroll
    for (int ci = 0; ci < 16; ci++) sv[ci] = f2bf(ldin(x, ci * DHW + dbase + p, bf));
    uint4 u0, u1;
    u0.x = (unsigned)sv[0] | ((unsigned)sv[1] << 16);
    u0.y = (unsigned)sv[2] | ((unsigned)sv[3] << 16);
    u0.z = (unsigned)sv[4] | ((unsigned)sv[5] << 16);
    u0.w = (unsigned)sv[6] | ((unsigned)sv[7] << 16);
    u1.x = (unsigned)sv[8] | ((unsigned)sv[9] << 16);
    u1.y = (unsigned)sv[10] | ((unsigned)sv[11] << 16);
    u1.z = (unsigned)sv[12] | ((unsigned)sv[13] << 16);
    u1.w = (unsigned)sv[14] | ((unsigned)sv[15] << 16);
    const size_t xb = (size_t)(dbase + p) * 16;
    *(uint4*)(xch16 + xb) = u0;
    *(uint4*)(xch16 + xb + 8) = u1;
  }

  float doff[18];
#pragma unroll
  for (int t = 0; t < 18; t++) doff[t] = 0.f;
  for (int ci = 0; ci < COFF; ci++) {
    const int fbase = ci * DHW + dbase;
#pragma unroll
    for (int ki = 0; ki < 3; ki++) {
      int yy = y - 1 + ki;
      bool yok = (unsigned)yy < (unsigned)H;
#pragma unroll
      for (int kj = 0; kj < 3; kj++) {
        int xj = xx - 1 + kj;
        float v = (yok && (unsigned)xj < (unsigned)W) ? ldin(f, fbase + yy * W + xj, bf) : 0.f;
        int widx = ci * 9 + ki * 3 + kj;
#pragma unroll
        for (int t = 0; t < 18; t++) doff[t] += v * w_off_t[widx * 18 + t];
      }
    }
  }

  float acc[COUT];
#pragma unroll
  for (int co = 0; co < COUT; co++) acc[co] = 0.f;

#pragma unroll
  for (int t = 0; t < 9; t++) {
    float dy = fminf(fmaxf(doff[2 * t], -1.f), 1.f);
    float dx = fminf(fmaxf(doff[2 * t + 1], -1.f), 1.f);
    float py = (float)(y - 1 + t / 3) + dy;
    float px = (float)(xx - 1 + t % 3) + dx;
    float y0f = floorf(py), x0f = floorf(px);
    float wy1 = py - y0f, wx1 = px - x0f;
    int y0 = (int)y0f, x0i = (int)x0f;
    int y1 = y0 + 1, x1 = x0i + 1;
    bool y0v = (unsigned)y0 < (unsigned)H, y1v = (unsigned)y1 < (unsigned)H;
    bool x0v = (unsigned)x0i < (unsigned)W, x1v = (unsigned)x1 < (unsigned)W;
    float c00 = (y0v && x0v) ? (1.f - wy1) * (1.f - wx1) : 0.f;
    float c01 = (y0v && x1v) ? (1.f - wy1) * wx1 : 0.f;
    float c10 = (y1v && x0v) ? wy1 * (1.f - wx1) : 0.f;
    float c11 = (y1v && x1v) ? wy1 * wx1 : 0.f;
    int y0c = min(max(y0, 0), H - 1) * W, y1c = min(max(y1, 0), H - 1) * W;
    int x0c = min(max(x0i, 0), W - 1), x1c = min(max(x1, 0), W - 1);

    for (int ci = 0; ci < CIN; ci++) {
      const int xbase = ci * DHW + dbase;
      float s = c00 * ldin(x, xbase + y0c + x0c, bf) + c01 * ldin(x, xbase + y0c + x1c, bf) +
                c10 * ldin(x, xbase + y1c + x0c, bf) + c11 * ldin(x, xbase + y1c + x1c, bf);
      const float* wp = w_reg_t + (ci * 9 + t) * 32;
#pragma unroll
      for (int co = 0; co < COUT; co++) acc[co] += s * wp[co];
    }
  }

  // store channels-last bf16
  u16 hh[COUT];
#pragma unroll
  for (int co = 0; co < COUT; co++) hh[co] = f2bf(acc[co]);
  const size_t pb = ((size_t)dbase + p) * 32;
#pragma unroll
  for (int k = 0; k < 4; k++) {
    uint4 u;
    u.x = (unsigned)hh[8 * k + 0] | ((unsigned)hh[8 * k + 1] << 16);
    u.y = (unsigned)hh[8 * k + 2] | ((unsigned)hh[8 * k + 3] << 16);
    u.z = (unsigned)hh[8 * k + 4] | ((unsigned)hh[8 * k + 5] << 16);
    u.w = (unsigned)hh[8 * k + 6] | ((unsigned)hh[8 * k + 7] << 16);
    *(uint4*)(a1ch + pb + 8 * k) = u;
  }

  // fused BN1 stats on bf16-rounded values
  const int l = threadIdx.x & 63;
  const int wv = threadIdx.x >> 6;
  __shared__ float ls[128], lq[128];
#pragma unroll
  for (int co = 0; co < COUT; co++) {
    float v = bf2f(hh[co]);
    float s = v, qq = v * v;
    s += __shfl_xor(s, 1);  qq += __shfl_xor(qq, 1);
    s += __shfl_xor(s, 2);  qq += __shfl_xor(qq, 2);
    s += __shfl_xor(s, 4);  qq += __shfl_xor(qq, 4);
    s += __shfl_xor(s, 8);  qq += __shfl_xor(qq, 8);
    s += __shfl_xor(s, 16); qq += __shfl_xor(qq, 16);
    s += __shfl_xor(s, 32); qq += __shfl_xor(qq, 32);
    if (l == 0) { ls[wv * 32 + co] = s; lq[wv * 32 + co] = qq; }
  }
  __syncthreads();
  if (threadIdx.x < 32) {
    int c = threadIdx.x;
    float s = ls[c] + ls[32 + c] + ls[64 + c] + ls[96 + c];
    float qq = lq[c] + lq[32 + c] + lq[64 + c] + lq[96 + c];
    atomicAdd(&S[c * D + d], s);
    atomicAdd(&S[1024 + c * D + d], qq);
  }
}

// BN1 apply; scale/offset computed in-block from raw sums (bit-identical)
__global__ __launch_bounds__(256) void bn1_apply_ch_kernel(u16* __restrict__ a1ch,
                                                           const float* __restrict__ S,
                                                           const float* __restrict__ g1f,
                                                           const float* __restrict__ b1f) {
  __shared__ float sc[32], of[32];
  const int b = blockIdx.x;
  const int d = b / (HW / 256);
  if (threadIdx.x < 32) {
    int c = threadIdx.x;
    float mean = S[c * D + d] / (float)HW;
    float var = S[1024 + c * D + d] / (float)HW - mean * mean;
    float scv = g1f[c] * rsqrtf(var + EPS);
    sc[c] = scv;
    of[c] = b1f[c] - mean * scv;
  }
  __syncthreads();
  const size_t pb = ((size_t)b * 256 + threadIdx.x) * 32;
#pragma unroll
  for (int k = 0; k < 4; k++) {
    uint4 u = *(const uint4*)(a1ch + pb + 8 * k);
    unsigned w[4] = {u.x, u.y, u.z, u.w};
    unsigned ov[4];
#pragma unroll
    for (int m = 0; m < 4; m++) {
      int c0 = k * 8 + m * 2;
      float lo = bf2f((u16)(w[m] & 0xffffu));
      float hi = bf2f((u16)(w[m] >> 16));
      lo = fmaxf(lo * sc[c0] + of[c0], 0.f);
      hi = fmaxf(hi * sc[c0 + 1] + of[c0 + 1], 0.f);
      ov[m] = (unsigned)f2bf(lo) | ((unsigned)f2bf(hi) << 16);
    }
    uint4 o;
    o.x = ov[0]; o.y = ov[1]; o.z = ov[2]; o.w = ov[3];
    *(uint4*)(a1ch + pb + 8 * k) = o;
  }
}

// legacy core for the two-pass fallback path (unchanged, proven)
static __device__ __forceinline__ void conv_core_lds(const bf16x8* __restrict__ a1v,
                                                     const bf16x8* __restrict__ xv16,
                                                     const bf16x8* __restrict__ w2s,  // LDS
                                                     const bf16x8* __restrict__ wdv,
                                                     int d, int y, int xn, int q, int l,
                                                     f32x4& A0, f32x4& A1, f32x4& B0, f32x4& B1) {
  const bf16x8 zero = {0, 0, 0, 0, 0, 0, 0, 0};
  const bool qlo = (q < 2);
#pragma unroll
  for (int kd = 0; kd < 3; kd++) {
    int dd = d - 1 + kd;
    if ((unsigned)dd >= (unsigned)D) continue;
#pragma unroll
    for (int ky = 0; ky < 3; ky++) {
      int yy = y - 1 + ky;
      if ((unsigned)yy >= (unsigned)H) continue;
      const int rowb = dd * HW + yy * W;
#pragma unroll
      for (int kx = 0; kx < 3; kx++) {
        int xx = xn - 1 + kx;
        bool ok = (unsigned)xx < (unsigned)W;
        int xc = min(max(xx, 0), W - 1);
        int pi = rowb + xc;
        bf16x8 bm = a1v[pi * 4 + q];
        bf16x8 bx = qlo ? xv16[pi * 2 + q] : zero;
        if (!ok) { bm = zero; bx = zero; }
        const int tb = (kd * 9 + ky * 3 + kx) * 2;
        bf16x8 am0 = w2s[(tb + 0) * 64 + l];
        bf16x8 am1 = w2s[(tb + 1) * 64 + l];
        bf16x8 ad0 = qlo ? wdv[(tb + 0) * 64 + l] : zero;
        bf16x8 ad1 = qlo ? wdv[(tb + 1) * 64 + l] : zero;
        A0 = __builtin_amdgcn_mfma_f32_16x16x32_bf16(am0, bm, A0, 0, 0, 0);
        A1 = __builtin_amdgcn_mfma_f32_16x16x32_bf16(am1, bm, A1, 0, 0, 0);
        B0 = __builtin_amdgcn_mfma_f32_16x16x32_bf16(ad0, bx, B0, 0, 0, 0);
        B1 = __builtin_amdgcn_mfma_f32_16x16x32_bf16(ad1, bx, B1, 0, 0, 0);
      }
    }
  }
}

#define STATS_RED(ACC, BASE)                                                          \
  {                                                                                   \
    _Pragma("unroll") for (int r = 0; r < 4; r++) {                                   \
      float v = ACC[r];                                                               \
      float s = v, qq = v * v;                                                        \
      s += __shfl_xor(s, 1); qq += __shfl_xor(qq, 1);                                 \
      s += __shfl_xor(s, 2); qq += __shfl_xor(qq, 2);                                 \
      s += __shfl_xor(s, 4); qq += __shfl_xor(qq, 4);                                 \
      s += __shfl_xor(s, 8); qq += __shfl_xor(qq, 8);                                 \
      if (n == 0) {                                                                   \
        int ci = (BASE) + q * 4 + r;                                                  \
        ls[wv * 64 + ci] = s;                                                         \
        lq[wv * 64 + ci] = qq;                                                        \
      }                                                                               \
    }                                                                                 \
  }

#define STATS_RED2(Aa, Ab, BASE)                                                      \
  {                                                                                   \
    _Pragma("unroll") for (int r = 0; r < 4; r++) {                                   \
      float v0 = Aa[r], v1 = Ab[r];                                                   \
      float s = v0 + v1, qq = v0 * v0 + v1 * v1;                                      \
      s += __shfl_xor(s, 1); qq += __shfl_xor(qq, 1);                                 \
      s += __shfl_xor(s, 2); qq += __shfl_xor(qq, 2);                                 \
      s += __shfl_xor(s, 4); qq += __shfl_xor(qq, 4);                                 \
      s += __shfl_xor(s, 8); qq += __shfl_xor(qq, 8);                                 \
      if (n == 0) {                                                                   \
        int ci = (BASE) + q * 4 + r;                                                  \
        ls[wv * 64 + ci] = s;                                                         \
        lq[wv * 64 + ci] = qq;                                                        \
      }                                                                               \
    }                                                                                 \
  }

// store-once (proven): 32 pixels (2 groups) per wave.
__global__ __launch_bounds__(1024) void conv_mfma_store_kernel(const u16* __restrict__ a1ch,
                                                               const u16* __restrict__ xch16,
                                                               const u16* __restrict__ w2f,
                                                               const u16* __restrict__ wdf,
                                                               float* __restrict__ A,
                                                               float* __restrict__ Bb,
                                                               float* __restrict__ S) {
  __shared__ u16 w2s[27648];  // 55296 B
  __shared__ float ls[16 * 64], lq[16 * 64];
  {
    const uint4* src = (const uint4*)w2f;
    uint4* dst = (uint4*)w2s;
    for (int i = threadIdx.x; i < 3456; i += 1024) dst[i] = src[i];
  }
  __syncthreads();

  const int hw = blockIdx.x;                 // grid = 1280, %8 == 0
  const int bid = (hw & 7) * 160 + (hw >> 3);
  const int t = threadIdx.x;
  const int l = t & 63, wv = t >> 6;
  const int n = l & 15, q = l >> 4;
  const int P0 = bid * 512 + wv * 32;        // 2 groups: P0, P0+16 (same d)
  const int d = P0 / HW;
  const int rp0 = P0 % HW;
  const int y0 = rp0 / W, x0 = rp0 % W;
  const int rp1 = (P0 + 16) % HW;
  const int y1g = rp1 / W, x1g = rp1 % W;

  const bf16x8 zero = {0, 0, 0, 0, 0, 0, 0, 0};
  const bool qlo = (q < 2);
  const bf16x8* a1v = (const bf16x8*)a1ch;
  const bf16x8* xv16 = (const bf16x8*)xch16;
  const bf16x8* w2v = (const bf16x8*)w2s;
  const bf16x8* wdv = (const bf16x8*)wdf;

  f32x4 aA0[2], aA1[2], aB0[2], aB1[2];
#pragma unroll
  for (int g = 0; g < 2; g++) {
    aA0[g] = (f32x4){0.f, 0.f, 0.f, 0.f};
    aA1[g] = (f32x4){0.f, 0.f, 0.f, 0.f};
    aB0[g] = (f32x4){0.f, 0.f, 0.f, 0.f};
    aB1[g] = (f32x4){0.f, 0.f, 0.f, 0.f};
  }

#pragma unroll
  for (int kd = 0; kd < 3; kd++) {
    int dd = d - 1 + kd;
    if ((unsigned)dd >= (unsigned)D) continue;
#pragma unroll
    for (int ky = 0; ky < 3; ky++) {
      int yy0 = y0 - 1 + ky, yy1 = y1g - 1 + ky;
      bool yok0 = (unsigned)yy0 < (unsigned)H, yok1 = (unsigned)yy1 < (unsigned)H;
      int rb0 = dd * HW + min(max(yy0, 0), H - 1) * W;
      int rb1 = dd * HW + min(max(yy1, 0), H - 1) * W;
#pragma unroll
      for (int kx = 0; kx < 3; kx++) {
        const int tb = (kd * 9 + ky * 3 + kx) * 2;
        bf16x8 am0 = w2v[(tb + 0) * 64 + l];
        bf16x8 am1 = w2v[(tb + 1) * 64 + l];
        bf16x8 ad0 = qlo ? wdv[(tb + 0) * 64 + l] : zero;
        bf16x8 ad1 = qlo ? wdv[(tb + 1) * 64 + l] : zero;
        {  // group 0
          int xx = x0 + n - 1 + kx;
          bool ok = yok0 && (unsigned)xx < (unsigned)W;
          int pi = rb0 + min(max(xx, 0), W - 1);
          bf16x8 bm = a1v[pi * 4 + q];
          bf16x8 bx = qlo ? xv16[pi * 2 + q] : zero;
          if (!ok) { bm = zero; bx = zero; }
          aA0[0] = __builtin_amdgcn_mfma_f32_16x16x32_bf16(am0, bm, aA0[0], 0, 0, 0);
          aA1[0] = __builtin_amdgcn_mfma_f32_16x16x32_bf16(am1, bm, aA1[0], 0, 0, 0);
          aB0[0] = __builtin_amdgcn_mfma_f32_16x16x32_bf16(ad0, bx, aB0[0], 0, 0, 0);
          aB1[0] = __builtin_amdgcn_mfma_f32_16x16x32_bf16(ad1, bx, aB1[0], 0, 0, 0);
        }
        {  // group 1
          int xx = x1g + n - 1 + kx;
          bool ok = yok1 && (unsigned)xx < (unsigned)W;
          int pi = rb1 + min(max(xx, 0), W - 1);
          bf16x8 bm = a1v[pi * 4 + q];
          bf16x8 bx = qlo ? xv16[pi * 2 + q] : zero;
          if (!ok) { bm = zero; bx = zero; }
          aA0[1] = __builtin_amdgcn_mfma_f32_16x16x32_bf16(am0, bm, aA0[1], 0, 0, 0);
          aA1[1] = __builtin_amdgcn_mfma_f32_16x16x32_bf16(am1, bm, aA1[1], 0, 0, 0);
          aB0[1] = __builtin_amdgcn_mfma_f32_16x16x32_bf16(ad0, bx, aB0[1], 0, 0, 0);
          aB1[1] = __builtin_amdgcn_mfma_f32_16x16x32_bf16(ad1, bx, aB1[1], 0, 0, 0);
        }
      }
    }
  }

#pragma unroll
  for (int g = 0; g < 2; g++) {
    const int Pg = P0 + 16 * g;
#pragma unroll
    for (int r = 0; r < 4; r++) {
      int co = q * 4 + r;
      A[co * DHW + Pg + n] = aA0[g][r];
      A[(co + 16) * DHW + Pg + n] = aA1[g][r];
      Bb[co * DHW + Pg + n] = aB0[g][r];
      Bb[(co + 16) * DHW + Pg + n] = aB1[g][r];
    }
  }

  STATS_RED2(aA0[0], aA0[1], 0)
  STATS_RED2(aA1[0], aA1[1], 16)
  STATS_RED2(aB0[0], aB0[1], 32)
  STATS_RED2(aB1[0], aB1[1], 48)
  __syncthreads();
  if (t < 64) {
    float s = 0.f, qq = 0.f;
    for (int w = 0; w < 16; w++) { s += ls[w * 64 + t]; qq += lq[w * 64 + t]; }
    if (t < 32) {
      atomicAdd(&S[2048 + t], s);
      atomicAdd(&S[2080 + t], qq);
    } else {
      atomicAdd(&S[2112 + t - 32], s);
      atomicAdd(&S[2144 + t - 32], qq);
    }
  }
}

// two-pass fallback: stats only (proven)
__global__ __launch_bounds__(1024) void conv_mfma_stats_kernel(const u16* __restrict__ a1ch,
                                                               const u16* __restrict__ xch16,
                                                               const u16* __restrict__ w2f,
                                                               const u16* __restrict__ wdf,
                                                               float* __restrict__ S) {
  __shared__ u16 w2s[27648];
  __shared__ float ls[16 * 64], lq[16 * 64];
  {
    const uint4* src = (const uint4*)w2f;
    uint4* dst = (uint4*)w2s;
    for (int i = threadIdx.x; i < 3456; i += 1024) dst[i] = src[i];
  }
  __syncthreads();

  const int hw = blockIdx.x;
  const int bid = (hw & 7) * 320 + (hw >> 3);
  const int t = threadIdx.x;
  const int l = t & 63, wv = t >> 6;
  const int n = l & 15, q = l >> 4;
  const int P = bid * 256 + wv * 16;
  const int d = P / HW;
  const int rp = P % HW;
  const int y = rp / W, xc0 = rp % W;

  f32x4 A0 = {0.f, 0.f, 0.f, 0.f}, A1 = {0.f, 0.f, 0.f, 0.f};
  f32x4 B0 = {0.f, 0.f, 0.f, 0.f}, B1 = {0.f, 0.f, 0.f, 0.f};
  conv_core_lds((const bf16x8*)a1ch, (const bf16x8*)xch16, (const bf16x8*)w2s,
                (const bf16x8*)wdf, d, y, xc0 + n, q, l, A0, A1, B0, B1);

  STATS_RED(A0, 0)
  STATS_RED(A1, 16)
  STATS_RED(B0, 32)
  STATS_RED(B1, 48)
  __syncthreads();
  if (t < 64) {
    float s = 0.f, qq = 0.f;
    for (int w = 0; w < 16; w++) { s += ls[w * 64 + t]; qq += lq[w * 64 + t]; }
    if (t < 32) {
      atomicAdd(&S[2048 + t], s);
      atomicAdd(&S[2080 + t], qq);
    } else {
      atomicAdd(&S[2112 + t - 32], s);
      atomicAdd(&S[2144 + t - 32], qq);
    }
  }
}

// fallback-only: finalize BN3 scales
__global__ void bn3_final_kernel(float* __restrict__ S, const float* __restrict__ g2f,
                                 const float* __restrict__ b2f, const float* __restrict__ gdf,
                                 const float* __restrict__ bdf) {
  int t = threadIdx.x;  // 64 threads
  if (t < 32) {
    float mean = S[2048 + t] / (float)DHW;
    float var = S[2080 + t] / (float)DHW - mean * mean;
    float sc = g2f[t] * rsqrtf(var + EPS);
    S[2176 + t] = sc;
    S[2208 + t] = b2f[t] - mean * sc;
  } else {
    int c = t - 32;
    float mean = S[2112 + c] / (float)DHW;
    float var = S[2144 + c] / (float)DHW - mean * mean;
    float sc = gdf[c] * rsqrtf(var + EPS);
    S[2240 + c] = sc;
    S[2272 + c] = bdf[c] - mean * sc;
  }
}

// store path: elementwise combine with BN3 finalize folded in (bit-identical)
__global__ __launch_bounds__(256) void combine32_kernel(const float* __restrict__ A,
                                                        const float* __restrict__ Bb,
                                                        const float* __restrict__ S,
                                                        const float* __restrict__ g2f,
                                                        const float* __restrict__ b2f,
                                                        const float* __restrict__ gdf,
                                                        const float* __restrict__ bdf,
                                                        const int* __restrict__ flagp,
                                                        void* __restrict__ out) {
  __shared__ float s2s[32], o2s[32], sds[32], ods[32];
  if (threadIdx.x < 64) {
    int t = threadIdx.x;
    if (t < 32) {
      float mean = S[2048 + t] / (float)DHW;
      float var = S[2080 + t] / (float)DHW - mean * mean;
      float sc = g2f[t] * rsqrtf(var + EPS);
      s2s[t] = sc;
      o2s[t] = b2f[t] - mean * sc;
    } else {
      int c = t - 32;
      float mean = S[2112 + c] / (float)DHW;
      float var = S[2144 + c] / (float)DHW - mean * mean;
      float sc = gdf[c] * rsqrtf(var + EPS);
      sds[c] = sc;
      ods[c] = bdf[c] - mean * sc;
    }
  }
  __syncthreads();

  int i = (blockIdx.x * 256 + threadIdx.x) * 4;
  int co = i / DHW;
  float s2 = s2s[co], o2 = o2s[co];
  float sd = sds[co], od = ods[co];
  float4 va = *(const float4*)(A + i);
  float4 vb = *(const float4*)(Bb + i);
  float r0 = fmaxf(va.x * s2 + o2 + vb.x * sd + od, 0.f);
  float r1 = fmaxf(va.y * s2 + o2 + vb.y * sd + od, 0.f);
  float r2 = fmaxf(va.z * s2 + o2 + vb.z * sd + od, 0.f);
  float r3 = fmaxf(va.w * s2 + o2 + vb.w * sd + od, 0.f);
  int bf = flagp[0];
  if (bf) {
    ushort4 st;
    st.x = f2bf(r0); st.y = f2bf(r1); st.z = f2bf(r2); st.w = f2bf(r3);
    *(ushort4*)((u16*)out + i) = st;
  } else {
    float4 st;
    st.x = r0; st.y = r1; st.z = r2; st.w = r3;
    *(float4*)((float*)out + i) = st;
  }
}

// two-pass fallback: recompute convs, fuse BN3 + add + relu (proven)
__global__ __launch_bounds__(256) void conv_mfma_final_kernel(const u16* __restrict__ a1ch,
                                                              const u16* __restrict__ xch16,
                                                              const u16* __restrict__ w2f,
                                                              const u16* __restrict__ wdf,
                                                              const float* __restrict__ S,
                                                              const int* __restrict__ flagp,
                                                              void* __restrict__ out) {
  __shared__ u16 w2s[27648];
  {
    const uint4* src = (const uint4*)w2f;
    uint4* dst = (uint4*)w2s;
    for (int i = threadIdx.x; i < 3456; i += 256) dst[i] = src[i];
  }
  __syncthreads();

  const int hw = blockIdx.x;                   // grid = 10240
  const int bid = (hw & 7) * 1280 + (hw >> 3);
  const int t = threadIdx.x;
  const int l = t & 63, wv = t >> 6;
  const int n = l & 15, q = l >> 4;
  const int P = bid * 64 + wv * 16;
  const int d = P / HW;
  const int rp = P % HW;
  const int y = rp / W, xc0 = rp % W;

  f32x4 A0 = {0.f, 0.f, 0.f, 0.f}, A1 = {0.f, 0.f, 0.f, 0.f};
  f32x4 B0 = {0.f, 0.f, 0.f, 0.f}, B1 = {0.f, 0.f, 0.f, 0.f};
  conv_core_lds((const bf16x8*)a1ch, (const bf16x8*)xch16, (const bf16x8*)w2s,
                (const bf16x8*)wdf, d, y, xc0 + n, q, l, A0, A1, B0, B1);

  const int bf = flagp[0];
#pragma unroll
  for (int r = 0; r < 4; r++) {
    int co = q * 4 + r;
    {
      float s2 = S[2176 + co], o2 = S[2208 + co];
      float sd = S[2240 + co], od = S[2272 + co];
      float v = fmaxf(A0[r] * s2 + o2 + B0[r] * sd + od, 0.f);
      int ai = co * DHW + P + n;
      if (bf) ((u16*)out)[ai] = f2bf(v);
      else ((float*)out)[ai] = v;
    }
    {
      int c2 = co + 16;
      float s2 = S[2176 + c2], o2 = S[2208 + c2];
      float sd = S[2240 + c2], od = S[2272 + c2];
      float v = fmaxf(A1[r] * s2 + o2 + B1[r] * sd + od, 0.f);
      int ai = c2 * DHW + P + n;
      if (bf) ((u16*)out)[ai] = f2bf(v);
      else ((float*)out)[ai] = v;
    }
  }
}

extern "C" void kernel_launch(void* const* d_in, const int* in_sizes, int n_in,
                              void* d_out, int out_size, void* d_ws, size_t ws_size,
                              hipStream_t stream) {
  const void* x = d_in[0];
  const void* f = d_in[1];

  char* ws = (char*)d_ws;
  float* S = (float*)ws;
  int* flag = (int*)ws + FLAG_SLOT;
  float* WF = (float*)(ws + WF_OFF);
  u16* a1ch = (u16*)(ws + A1CH_OFF);
  u16* xch16 = (u16*)(ws + XCH16_OFF);

  init_kernel<<<17, 256, 0, stream>>>(S, (const u16*)x, flag);

  const int store = (ws_size >= NEED_STORE) ? 1 : 0;
  u16* w2frag = (u16*)(ws + (store ? FRAGS_W2 : FRAG2P_W2));
  u16* wdfrag = (u16*)(ws + (store ? FRAGS_WD : FRAG2P_WD));

  // inputs: x,f,w_off,w_reg,g1,b1,w2,g2,b2,wd,gd,bd
  prep_kernel<<<245, 256, 0, stream>>>(d_in[2], d_in[3], d_in[6], d_in[9], d_in[4], d_in[5],
                                       d_in[7], d_in[8], d_in[10], d_in[11], WF, w2frag, wdfrag,
                                       flag);

  deform_chm_kernel<<<2560, 256, 0, stream>>>(x, f, WF + WOFFT_O, WF + WREGT_O, a1ch, xch16,
                                              flag, S);
  bn1_apply_ch_kernel<<<DHW / 256, 256, 0, stream>>>(a1ch, S, WF + G1_O, WF + B1_O);

  if (store) {
    float* A = (float*)(ws + STA_OFF);
    float* Bb = (float*)(ws + STB_OFF);
    conv_mfma_store_kernel<<<1280, 1024, 0, stream>>>(a1ch, xch16, w2frag, wdfrag, A, Bb, S);
    combine32_kernel<<<NOUT / 1024, 256, 0, stream>>>(A, Bb, S, WF + G2_O, WF + B2_O, WF + GD_O,
                                                      WF + BD_O, flag, d_out);
  } else {
    conv_mfma_stats_kernel<<<2560, 1024, 0, stream>>>(a1ch, xch16, w2frag, wdfrag, S);
    bn3_final_kernel<<<1, 64, 0, stream>>>(S, WF + G2_O, WF + B2_O, WF + GD_O, WF + BD_O);
    conv_mfma_final_kernel<<<10240, 256, 0, stream>>>(a1ch, xch16, w2frag, wdfrag, S, flag,
                                                      d_out);
  }
}